// Round 13
// baseline (176.577 us; speedup 1.0000x reference)
//
#include <hip/hip_runtime.h>
#include <stdint.h>
#include <math.h>

#define BH_ 16
#define N_  2048
#define D_  64
#define NEGV (-1e15f)

typedef __attribute__((ext_vector_type(8))) short bf16x8;
typedef __attribute__((ext_vector_type(8))) unsigned short us8;
typedef __attribute__((ext_vector_type(4))) float f32x4;

// ---------------- workspace layout ----------------
#define OFF_MASKU8 0u
#define OFF_MBITS  32768u                // 16*32 u64
#define OFF_EBITS  65536u                // 2*2048*128 u16 = 1 MB
#define OFF_QBF    1114112u              // 4 MB bf16
#define OFF_KBF    5308416u              // 4 MB
#define OFF_VT     9502720u              // 4 MB (transposed [bh][d][n])
#define WS_V6      13697024u
#define OFF_PU     13697024u             // 16*2048*2048 bf16 = 134.2 MB (L3-resident)
#define WS_V10     147914752u

// Barrier WITHOUT the implicit vmcnt(0) drain of __syncthreads: LDS visibility
// only (lgkmcnt). Global stores/loads stay in flight across it.
#define BARRIER_LGKM() do {                                   \
    asm volatile("s_waitcnt lgkmcnt(0)" ::: "memory");        \
    __builtin_amdgcn_sched_barrier(0);                        \
    __builtin_amdgcn_s_barrier();                             \
    __builtin_amdgcn_sched_barrier(0);                        \
} while (0)

__device__ __forceinline__ unsigned short f2bf(float f) {
    unsigned u = __float_as_uint(f);
    return (unsigned short)((u + 0x7FFFu + ((u >> 16) & 1u)) >> 16);   // RNE
}
__device__ __forceinline__ float bf2f(short s) {
    return __uint_as_float(((unsigned)(unsigned short)s) << 16);
}

// ---- fused prepass: edge pack (blocks 0..2047), q/k/v convert (2048..2559),
//      mask pack+detect (2560..2575)
__global__ __launch_bounds__(256)
void prep_all(const float* __restrict__ q, const float* __restrict__ k,
              const float* __restrict__ v, const void* __restrict__ mraw,
              const int* __restrict__ edge,
              unsigned short* __restrict__ qbf, unsigned short* __restrict__ kbf,
              unsigned short* __restrict__ vT,
              unsigned short* __restrict__ e16, unsigned long long* __restrict__ mbits)
{
    __shared__ unsigned short shbuf[64][72];
    __shared__ int flag;
    const int bid = blockIdx.x;
    const int t   = threadIdx.x;

    if (bid < 2048) {               // ---- edge -> u16 bitmasks (thread-local)
        const int idx = bid * 256 + t;            // 0..524287
        const int4* p = (const int4*)(edge + (size_t)idx * 16);
        unsigned m = 0;
        #pragma unroll
        for (int i = 0; i < 4; ++i) {
            const int4 vv = p[i];
            m |= (vv.x != 0 ? 1u : 0u) << (i * 4 + 0);
            m |= (vv.y != 0 ? 1u : 0u) << (i * 4 + 1);
            m |= (vv.z != 0 ? 1u : 0u) << (i * 4 + 2);
            m |= (vv.w != 0 ? 1u : 0u) << (i * 4 + 3);
        }
        e16[idx] = (unsigned short)m;
    } else if (bid < 2560) {        // ---- q,k -> bf16; v -> bf16 transposed
        const int b2 = bid - 2048;
        const int rt = b2 & 31, bh = b2 >> 5;
        const size_t base = ((size_t)bh * N_ + (size_t)rt * 64) * D_;
        #pragma unroll
        for (int i = 0; i < 4; ++i) {
            const int idx = t + i * 256;
            float4 f = *(const float4*)(q + base + (size_t)idx * 4);
            ushort4 s; s.x = f2bf(f.x); s.y = f2bf(f.y); s.z = f2bf(f.z); s.w = f2bf(f.w);
            *(ushort4*)(qbf + base + (size_t)idx * 4) = s;
            f = *(const float4*)(k + base + (size_t)idx * 4);
            s.x = f2bf(f.x); s.y = f2bf(f.y); s.z = f2bf(f.z); s.w = f2bf(f.w);
            *(ushort4*)(kbf + base + (size_t)idx * 4) = s;
            f = *(const float4*)(v + base + (size_t)idx * 4);
            const int row = idx >> 4;
            const int d0  = (idx & 15) * 4;
            shbuf[d0 + 0][row] = f2bf(f.x);
            shbuf[d0 + 1][row] = f2bf(f.y);
            shbuf[d0 + 2][row] = f2bf(f.z);
            shbuf[d0 + 3][row] = f2bf(f.w);
        }
        __syncthreads();
        const int d  = t >> 2;
        const int c4 = (t & 3) * 16;
        const size_t ob = ((size_t)bh * D_ + d) * N_ + (size_t)rt * 64 + c4;
        *(us8*)(vT + ob)     = *(us8*)&shbuf[d][c4];
        *(us8*)(vT + ob + 8) = *(us8*)&shbuf[d][c4 + 8];
    } else {                        // ---- mask detect + pack
        const int bh = bid - 2560;
        if (t == 0) flag = 0;
        __syncthreads();
        const int* mi = (const int*)mraw;
        int bad = 0;
        for (int i = t; i < 8192; i += 256)
            if ((unsigned)mi[i] > 1u) bad = 1;
        if (bad) atomicOr(&flag, 1);
        __syncthreads();
        const int is_u8 = flag;
        const uint8_t* m8 = (const uint8_t*)mraw;
        const int w4 = t >> 6, l = t & 63;
        for (int it = 0; it < 8; ++it) {
            const int pos = bh * 2048 + it * 256 + w4 * 64 + l;
            const bool on = is_u8 ? (m8[pos] != 0) : (mi[pos] != 0);
            unsigned long long bal = __ballot(on);
            if (l == 0) mbits[bh * 32 + it * 4 + w4] = bal;
        }
    }
}

// ---- main v10: v8 structure, but pass 1 caches UNNORMALIZED exp (bf16) in ws
// (Pu, L3-resident). Pass 2 then needs NO K staging / QK^T / exp: Pu rows are
// loaded directly as MFMA A-fragments, scaled by inv for the attn store, and
// fed raw into PV; o normalized once at the epilogue via per-row invA.
__global__ __launch_bounds__(256)
void attn_v10(const unsigned short* __restrict__ qbf,
              const unsigned short* __restrict__ kbf,
              const unsigned short* __restrict__ vT,
              const unsigned long long* __restrict__ ebits,
              const unsigned long long* __restrict__ mbits,
              unsigned short* __restrict__ pu,
              float* __restrict__ out, float* __restrict__ attn)
{
    __shared__ unsigned short sKV[2][4096];  // pass1: K dbuf; pass2: V dbuf
    __shared__ float invA[4][16];

    const int bh   = blockIdx.x;    // FASTEST -> XCD = bh % 8 (T1 locality)
    const int tile = blockIdx.y;    // 0..31
    const int t    = threadIdx.x;
    const int w    = t >> 6;
    const int lane = t & 63;
    const int l15  = lane & 15;
    const int lg   = lane >> 4;
    const int rbase = tile * 64;
    const int myrow = rbase + w * 16 + l15;

    const unsigned short* qb = qbf + (size_t)bh * N_ * D_;
    const unsigned short* kb = kbf + (size_t)bh * N_ * D_;
    const unsigned short* vb = vT  + (size_t)bh * D_ * N_;
    const unsigned long long* ebrow =
        ebits + ((size_t)(bh & 1) * N_ + (size_t)myrow) * 32;
    const unsigned long long* mb = mbits + bh * 32;
    float* outb = out + (size_t)bh * N_ * D_;
    float* arow = attn + ((size_t)bh * N_ + myrow) * N_;
    unsigned short* purow = pu + ((size_t)bh * N_ + myrow) * N_;

    // Q fragments (B-operand of swapped QK^T), row = myrow
    const bf16x8 aq0 = *(const bf16x8*)(qb + (size_t)myrow * D_ + lg * 8);
    const bf16x8 aq1 = *(const bf16x8*)(qb + (size_t)myrow * D_ + lg * 8 + 32);

    // cooperative staging: thread t covers 16B slots t and t+256 of each 8KB tile
    const int s0row = t >> 3;               // 0..31
    const int s1row = s0row + 32;           // 32..63
    const int t8    = t & 7;
    const int ds0 = s0row * 64 + ((t8 ^ (s0row & 7)) * 8);
    const int ds1 = s1row * 64 + ((t8 ^ (s1row & 7)) * 8);

    // =============== PASS 1: row sums of exp + Pu store ===============
    {
        *(us8*)(sKV[0] + ds0) = *(const us8*)(kb + (size_t)t * 8);
        *(us8*)(sKV[0] + ds1) = *(const us8*)(kb + (size_t)(t + 256) * 8);
        BARRIER_LGKM();
    }
    float lacc = 0.f;
    #pragma unroll 1
    for (int kc = 0; kc < 32; ++kc) {
        const int cur = kc & 1;
        us8 nk0, nk1;
        if (kc < 31) {
            const unsigned short* s = kb + (size_t)(kc + 1) * 4096;
            nk0 = *(const us8*)(s + (size_t)t * 8);
            nk1 = *(const us8*)(s + (size_t)(t + 256) * 8);
        }
        const unsigned long long wbits = ebrow[kc] & ~mb[kc];
        const unsigned short* kcur = sKV[cur];
        #pragma unroll
        for (int nt = 0; nt < 4; ++nt) {
            const int row = nt * 16 + l15, sw = row & 7;
            const bf16x8 k0 = *(const bf16x8*)(kcur + row * 64 + ((lg ^ sw) * 8));
            const bf16x8 k1 = *(const bf16x8*)(kcur + row * 64 + (((lg + 4) ^ sw) * 8));
            f32x4 c = (f32x4){0.f, 0.f, 0.f, 0.f};
            c = __builtin_amdgcn_mfma_f32_16x16x32_bf16(k0, aq0, c, 0, 0, 0);
            c = __builtin_amdgcn_mfma_f32_16x16x32_bf16(k1, aq1, c, 0, 0, 0);
            const unsigned bits = (unsigned)(wbits >> (nt * 16 + lg * 4)) & 0xFu;
            const float e0 = (bits & 1u) ? __expf(c[0] * 0.125f) : 0.f;
            const float e1 = (bits & 2u) ? __expf(c[1] * 0.125f) : 0.f;
            const float e2 = (bits & 4u) ? __expf(c[2] * 0.125f) : 0.f;
            const float e3 = (bits & 8u) ? __expf(c[3] * 0.125f) : 0.f;
            lacc += (e0 + e1) + (e2 + e3);
            ushort4 pe;
            pe.x = f2bf(e0); pe.y = f2bf(e1); pe.z = f2bf(e2); pe.w = f2bf(e3);
            *(ushort4*)(purow + kc * 64 + nt * 16 + lg * 4) = pe;  // unnormalized
        }
        if (kc < 31) {
            *(us8*)(sKV[cur ^ 1] + ds0) = nk0;
            *(us8*)(sKV[cur ^ 1] + ds1) = nk1;
        }
        BARRIER_LGKM();
    }
    lacc += __shfl_xor(lacc, 16);
    lacc += __shfl_xor(lacc, 32);
    const float inv = 1.0f / lacc;     // full row sum for row myrow
    if (lg == 0) invA[w][l15] = inv;   // per-row table for epilogue (same-wave DS)

    // make this wave's Pu stores globally visible before re-reading them
    asm volatile("s_waitcnt vmcnt(0)" ::: "memory");
    __builtin_amdgcn_sched_barrier(0);

    // =============== PASS 2: V-only staging; Pu -> attn + PV ===============
    {
        *(us8*)(sKV[0] + ds0) = *(const us8*)(vb + (size_t)s0row * 2048 + t8 * 8);
        *(us8*)(sKV[0] + ds1) = *(const us8*)(vb + (size_t)s1row * 2048 + t8 * 8);
        BARRIER_LGKM();
    }

    f32x4 o[4];
    #pragma unroll
    for (int nt = 0; nt < 4; ++nt) o[nt] = (f32x4){0.f, 0.f, 0.f, 0.f};

    #pragma unroll 1
    for (int kc = 0; kc < 32; ++kc) {
        const int cur = kc & 1;
        us8 nv0, nv1;
        if (kc < 31) {   // V loads issued FIRST (oldest vmem of this chunk)
            const unsigned short* srcv = vb + (size_t)(kc + 1) * 64;
            nv0 = *(const us8*)(srcv + (size_t)s0row * 2048 + t8 * 8);
            nv1 = *(const us8*)(srcv + (size_t)s1row * 2048 + t8 * 8);
        }
        // Pu A-fragments: lane l15,lg holds P[myrow][kc*64 + lg*8 .. +7] (+32)
        const bf16x8 ap0 = *(const bf16x8*)(purow + kc * 64 + lg * 8);
        const bf16x8 ap1 = *(const bf16x8*)(purow + kc * 64 + lg * 8 + 32);
        // attn = float(Pu) * inv  (16 floats, 4x float4, row myrow)
        {
            float4 f0, f1, f2, f3;
            f0.x = bf2f(ap0[0]) * inv; f0.y = bf2f(ap0[1]) * inv;
            f0.z = bf2f(ap0[2]) * inv; f0.w = bf2f(ap0[3]) * inv;
            f1.x = bf2f(ap0[4]) * inv; f1.y = bf2f(ap0[5]) * inv;
            f1.z = bf2f(ap0[6]) * inv; f1.w = bf2f(ap0[7]) * inv;
            f2.x = bf2f(ap1[0]) * inv; f2.y = bf2f(ap1[1]) * inv;
            f2.z = bf2f(ap1[2]) * inv; f2.w = bf2f(ap1[3]) * inv;
            f3.x = bf2f(ap1[4]) * inv; f3.y = bf2f(ap1[5]) * inv;
            f3.z = bf2f(ap1[6]) * inv; f3.w = bf2f(ap1[7]) * inv;
            float* astore = arow + kc * 64 + lg * 8;
            *(float4*)(astore)      = f0;
            *(float4*)(astore + 4)  = f1;
            *(float4*)(astore + 32) = f2;
            *(float4*)(astore + 36) = f3;
        }
        // PV: unnormalized Pu x V d-slices (o normalized at epilogue)
        const unsigned short* vcur = sKV[cur];
        #pragma unroll
        for (int nt = 0; nt < 4; ++nt) {
            const int row = nt * 16 + l15, sw = row & 7;   // d-row
            const bf16x8 bv0 = *(const bf16x8*)(vcur + row * 64 + ((lg ^ sw) * 8));
            const bf16x8 bv1 = *(const bf16x8*)(vcur + row * 64 + (((lg + 4) ^ sw) * 8));
            o[nt] = __builtin_amdgcn_mfma_f32_16x16x32_bf16(ap0, bv0, o[nt], 0, 0, 0);
            o[nt] = __builtin_amdgcn_mfma_f32_16x16x32_bf16(ap1, bv1, o[nt], 0, 0, 0);
        }
        if (kc < 31) {
            *(us8*)(sKV[cur ^ 1] + ds0) = nv0;
            *(us8*)(sKV[cur ^ 1] + ds1) = nv1;
        }
        BARRIER_LGKM();
    }

    // epilogue: normalize o by per-row inv (rows lg*4+r), wave-local invA
    const float i0 = invA[w][lg * 4 + 0];
    const float i1 = invA[w][lg * 4 + 1];
    const float i2 = invA[w][lg * 4 + 2];
    const float i3 = invA[w][lg * 4 + 3];
    #pragma unroll
    for (int nt = 0; nt < 4; ++nt) {
        outb[(size_t)(rbase + w * 16 + lg * 4 + 0) * D_ + nt * 16 + l15] = o[nt][0] * i0;
        outb[(size_t)(rbase + w * 16 + lg * 4 + 1) * D_ + nt * 16 + l15] = o[nt][1] * i1;
        outb[(size_t)(rbase + w * 16 + lg * 4 + 2) * D_ + nt * 16 + l15] = o[nt][2] * i2;
        outb[(size_t)(rbase + w * 16 + lg * 4 + 3) * D_ + nt * 16 + l15] = o[nt][3] * i3;
    }
}

// ================= v8 (mid fallback, verified round 11, 121 us) =================
__global__ __launch_bounds__(256)
void attn_v8(const unsigned short* __restrict__ qbf,
             const unsigned short* __restrict__ kbf,
             const unsigned short* __restrict__ vT,
             const unsigned long long* __restrict__ ebits,
             const unsigned long long* __restrict__ mbits,
             float* __restrict__ out, float* __restrict__ attn)
{
    __shared__ unsigned short sK[2][4096];
    __shared__ unsigned short sV[2][4096];
    __shared__ char pbuf[4][2048];

    const int bh   = blockIdx.x;
    const int tile = blockIdx.y;
    const int t    = threadIdx.x;
    const int w    = t >> 6;
    const int lane = t & 63;
    const int l15  = lane & 15;
    const int lg   = lane >> 4;
    const int rbase = tile * 64;
    const int myrow = rbase + w * 16 + l15;

    const unsigned short* qb = qbf + (size_t)bh * N_ * D_;
    const unsigned short* kb = kbf + (size_t)bh * N_ * D_;
    const unsigned short* vb = vT  + (size_t)bh * D_ * N_;
    const unsigned long long* ebrow =
        ebits + ((size_t)(bh & 1) * N_ + (size_t)myrow) * 32;
    const unsigned long long* mb = mbits + bh * 32;
    float* outb = out + (size_t)bh * N_ * D_;
    float* arow = attn + (size_t)bh * N_ * N_ + (size_t)myrow * N_ + lg * 4;

    const bf16x8 aq0 = *(const bf16x8*)(qb + (size_t)myrow * D_ + lg * 8);
    const bf16x8 aq1 = *(const bf16x8*)(qb + (size_t)myrow * D_ + lg * 8 + 32);

    const int s0row = t >> 3;
    const int s1row = s0row + 32;
    const int t8    = t & 7;
    const int ds0 = s0row * 64 + ((t8 ^ (s0row & 7)) * 8);
    const int ds1 = s1row * 64 + ((t8 ^ (s1row & 7)) * 8);

    {
        *(us8*)(sK[0] + ds0) = *(const us8*)(kb + (size_t)t * 8);
        *(us8*)(sK[0] + ds1) = *(const us8*)(kb + (size_t)(t + 256) * 8);
        BARRIER_LGKM();
    }
    float lacc = 0.f;
    #pragma unroll 1
    for (int kc = 0; kc < 32; ++kc) {
        const int cur = kc & 1;
        us8 nk0, nk1;
        if (kc < 31) {
            const unsigned short* s = kb + (size_t)(kc + 1) * 4096;
            nk0 = *(const us8*)(s + (size_t)t * 8);
            nk1 = *(const us8*)(s + (size_t)(t + 256) * 8);
        }
        const unsigned long long wbits = ebrow[kc] & ~mb[kc];
        const unsigned short* kcur = sK[cur];
        #pragma unroll
        for (int nt = 0; nt < 4; ++nt) {
            const int row = nt * 16 + l15, sw = row & 7;
            const bf16x8 k0 = *(const bf16x8*)(kcur + row * 64 + ((lg ^ sw) * 8));
            const bf16x8 k1 = *(const bf16x8*)(kcur + row * 64 + (((lg + 4) ^ sw) * 8));
            f32x4 c = (f32x4){0.f, 0.f, 0.f, 0.f};
            c = __builtin_amdgcn_mfma_f32_16x16x32_bf16(k0, aq0, c, 0, 0, 0);
            c = __builtin_amdgcn_mfma_f32_16x16x32_bf16(k1, aq1, c, 0, 0, 0);
            const unsigned bits = (unsigned)(wbits >> (nt * 16 + lg * 4)) & 0xFu;
            #pragma unroll
            for (int r = 0; r < 4; ++r)
                lacc += ((bits >> r) & 1u) ? __expf(c[r] * 0.125f) : 0.f;
        }
        if (kc < 31) {
            *(us8*)(sK[cur ^ 1] + ds0) = nk0;
            *(us8*)(sK[cur ^ 1] + ds1) = nk1;
        }
        BARRIER_LGKM();
    }
    lacc += __shfl_xor(lacc, 16);
    lacc += __shfl_xor(lacc, 32);
    const float inv = 1.0f / lacc;

    {
        *(us8*)(sK[0] + ds0) = *(const us8*)(kb + (size_t)t * 8);
        *(us8*)(sK[0] + ds1) = *(const us8*)(kb + (size_t)(t + 256) * 8);
        *(us8*)(sV[0] + ds0) = *(const us8*)(vb + (size_t)s0row * 2048 + t8 * 8);
        *(us8*)(sV[0] + ds1) = *(const us8*)(vb + (size_t)s1row * 2048 + t8 * 8);
        BARRIER_LGKM();
    }

    f32x4 o[4];
    #pragma unroll
    for (int nt = 0; nt < 4; ++nt) o[nt] = (f32x4){0.f, 0.f, 0.f, 0.f};

    char* pbw = pbuf[w];
    const int swzP = (l15 & 7) << 4;
    const int ab0 = (l15 * 128 + lg * 16)      ^ swzP;
    const int ab1 = (l15 * 128 + lg * 16 + 64) ^ swzP;

    #pragma unroll 1
    for (int kc = 0; kc < 32; ++kc) {
        const int cur = kc & 1;
        us8 nk0, nk1, nv0, nv1;
        if (kc < 31) {
            const unsigned short* srck = kb + (size_t)(kc + 1) * 4096;
            const unsigned short* srcv = vb + (size_t)(kc + 1) * 64;
            nk0 = *(const us8*)(srck + (size_t)t * 8);
            nk1 = *(const us8*)(srck + (size_t)(t + 256) * 8);
            nv0 = *(const us8*)(srcv + (size_t)s0row * 2048 + t8 * 8);
            nv1 = *(const us8*)(srcv + (size_t)s1row * 2048 + t8 * 8);
        }
        const unsigned long long wbits = ebrow[kc] & ~mb[kc];
        const unsigned short* kcur = sK[cur];
        float4 ev[4];
        #pragma unroll
        for (int nt = 0; nt < 4; ++nt) {
            const int row = nt * 16 + l15, sw = row & 7;
            const bf16x8 k0 = *(const bf16x8*)(kcur + row * 64 + ((lg ^ sw) * 8));
            const bf16x8 k1 = *(const bf16x8*)(kcur + row * 64 + (((lg + 4) ^ sw) * 8));
            f32x4 c = (f32x4){0.f, 0.f, 0.f, 0.f};
            c = __builtin_amdgcn_mfma_f32_16x16x32_bf16(k0, aq0, c, 0, 0, 0);
            c = __builtin_amdgcn_mfma_f32_16x16x32_bf16(k1, aq1, c, 0, 0, 0);
            const unsigned bits = (unsigned)(wbits >> (nt * 16 + lg * 4)) & 0xFu;
            float4 e;
            e.x = (bits & 1u) ? __expf(c[0] * 0.125f) * inv : 0.f;
            e.y = (bits & 2u) ? __expf(c[1] * 0.125f) * inv : 0.f;
            e.z = (bits & 4u) ? __expf(c[2] * 0.125f) * inv : 0.f;
            e.w = (bits & 8u) ? __expf(c[3] * 0.125f) * inv : 0.f;
            ev[nt] = e;
            ushort4 pe;
            pe.x = f2bf(e.x); pe.y = f2bf(e.y); pe.z = f2bf(e.z); pe.w = f2bf(e.w);
            const int wbyte = (l15 * 128 + nt * 32 + lg * 8) ^ swzP;
            *(ushort4*)(pbw + wbyte) = pe;
        }
        const bf16x8 ap0 = *(const bf16x8*)(pbw + ab0);
        const bf16x8 ap1 = *(const bf16x8*)(pbw + ab1);
        const unsigned short* vcur = sV[cur];
        #pragma unroll
        for (int nt = 0; nt < 4; ++nt) {
            const int row = nt * 16 + l15, sw = row & 7;
            const bf16x8 bv0 = *(const bf16x8*)(vcur + row * 64 + ((lg ^ sw) * 8));
            const bf16x8 bv1 = *(const bf16x8*)(vcur + row * 64 + (((lg + 4) ^ sw) * 8));
            o[nt] = __builtin_amdgcn_mfma_f32_16x16x32_bf16(ap0, bv0, o[nt], 0, 0, 0);
            o[nt] = __builtin_amdgcn_mfma_f32_16x16x32_bf16(ap1, bv1, o[nt], 0, 0, 0);
        }
        {
            float* astore = arow + kc * 64;
            #pragma unroll
            for (int nt = 0; nt < 4; ++nt)
                *(float4*)(astore + nt * 16) = ev[nt];
        }
        if (kc < 31) {
            *(us8*)(sK[cur ^ 1] + ds0) = nk0;
            *(us8*)(sK[cur ^ 1] + ds1) = nk1;
            *(us8*)(sV[cur ^ 1] + ds0) = nv0;
            *(us8*)(sV[cur ^ 1] + ds1) = nv1;
        }
        BARRIER_LGKM();
    }

    #pragma unroll
    for (int nt = 0; nt < 4; ++nt)
        #pragma unroll
        for (int r = 0; r < 4; ++r)
            outb[(size_t)(rbase + w * 16 + lg * 4 + r) * D_ + nt * 16 + l15] = o[nt][r];
}

// ================= fp32 deep fallback (needs only 32 KB ws) =================
__global__ __launch_bounds__(256)
void normalize_mask(const void* __restrict__ mask_raw, uint8_t* __restrict__ mask_out)
{
    __shared__ int is_u8;
    const int t = threadIdx.x;
    if (t == 0) is_u8 = 0;
    __syncthreads();
    const int* mi = (const int*)mask_raw;
    int bad = 0;
    for (int i = t; i < 8192; i += 256)
        if ((unsigned)mi[i] > 1u) bad = 1;
    if (bad) atomicOr(&is_u8, 1);
    __syncthreads();
    const int total = BH_ * N_;
    if (is_u8) {
        const uint8_t* m8 = (const uint8_t*)mask_raw;
        for (int i = t; i < total; i += 256) mask_out[i] = m8[i] ? 1 : 0;
    } else {
        for (int i = t; i < total; i += 256) mask_out[i] = (uint8_t)mi[i];
    }
}

__global__ __launch_bounds__(256)
void attn_fused(const float* __restrict__ q, const float* __restrict__ k,
                const float* __restrict__ v, const uint8_t* __restrict__ mask,
                const int* __restrict__ edge, float* __restrict__ out,
                float* __restrict__ attn)
{
    __shared__ float qsT[D_][64 + 4];
    __shared__ float kt [D_][64 + 4];
    __shared__ float vs [64][D_ + 4];
    const int tile = blockIdx.x, bh = blockIdx.y, t = threadIdx.x;
    const int rg = t >> 4, cg = t & 15, r0 = rg * 4, c0 = cg * 4;
    const int row_base = tile * 64;
    const float* qb = q + (size_t)bh * N_ * D_;
    const float* kb = k + (size_t)bh * N_ * D_;
    const float* vb = v + (size_t)bh * N_ * D_;
    const uint8_t* mbp = mask + (size_t)bh * N_;
    const int* ebp = edge + (size_t)(bh & 1) * N_ * N_;
    float* outb = out + (size_t)bh * N_ * D_;
    float* attnb = attn + (size_t)bh * N_ * N_;
    {
        const int rr = t >> 2, dblk = (t & 3) * 16;
        const float* src = qb + (size_t)(row_base + rr) * D_ + dblk;
        #pragma unroll
        for (int qq = 0; qq < 4; ++qq) {
            float4 val = *(const float4*)(src + qq * 4);
            qsT[dblk + qq*4 + 0][rr] = val.x; qsT[dblk + qq*4 + 1][rr] = val.y;
            qsT[dblk + qq*4 + 2][rr] = val.z; qsT[dblk + qq*4 + 3][rr] = val.w;
        }
    }
    float m_i[4], l_i[4];
    #pragma unroll
    for (int i = 0; i < 4; ++i) { m_i[i] = -INFINITY; l_i[i] = 0.f; }
    for (int kc = 0; kc < 32; ++kc) {
        __syncthreads();
        {
            const int ccr = t >> 2, dblk = (t & 3) * 16;
            const float* src = kb + (size_t)(kc * 64 + ccr) * D_ + dblk;
            #pragma unroll
            for (int qq = 0; qq < 4; ++qq) {
                float4 val = *(const float4*)(src + qq * 4);
                kt[dblk + qq*4 + 0][ccr] = val.x; kt[dblk + qq*4 + 1][ccr] = val.y;
                kt[dblk + qq*4 + 2][ccr] = val.z; kt[dblk + qq*4 + 3][ccr] = val.w;
            }
        }
        __syncthreads();
        float sc[4][4];
        #pragma unroll
        for (int i = 0; i < 4; ++i) { sc[i][0]=sc[i][1]=sc[i][2]=sc[i][3]=0.f; }
        for (int d = 0; d < D_; ++d) {
            const float4 qv = *(const float4*)&qsT[d][r0];
            const float4 kv = *(const float4*)&kt[d][c0];
            #pragma unroll
            for (int i = 0; i < 4; ++i) {
                const float qi = (i==0)?qv.x:(i==1)?qv.y:(i==2)?qv.z:qv.w;
                sc[i][0] = fmaf(qi, kv.x, sc[i][0]); sc[i][1] = fmaf(qi, kv.y, sc[i][1]);
                sc[i][2] = fmaf(qi, kv.z, sc[i][2]); sc[i][3] = fmaf(qi, kv.w, sc[i][3]);
            }
        }
        const int cbase = kc * 64 + c0;
        const uint8_t m0 = mbp[cbase], m1 = mbp[cbase+1], m2 = mbp[cbase+2], m3 = mbp[cbase+3];
        #pragma unroll
        for (int i = 0; i < 4; ++i) {
            const int rglob = row_base + r0 + i;
            const int4 e4 = *(const int4*)(ebp + (size_t)rglob * N_ + cbase);
            float s0 = sc[i][0]*0.125f, s1 = sc[i][1]*0.125f, s2 = sc[i][2]*0.125f, s3 = sc[i][3]*0.125f;
            if (e4.x == 0 || m0) s0 = NEGV; if (e4.y == 0 || m1) s1 = NEGV;
            if (e4.z == 0 || m2) s2 = NEGV; if (e4.w == 0 || m3) s3 = NEGV;
            float cmax = fmaxf(fmaxf(s0,s1), fmaxf(s2,s3));
            cmax = fmaxf(cmax, __shfl_xor(cmax,1)); cmax = fmaxf(cmax, __shfl_xor(cmax,2));
            cmax = fmaxf(cmax, __shfl_xor(cmax,4)); cmax = fmaxf(cmax, __shfl_xor(cmax,8));
            const float nm = fmaxf(m_i[i], cmax);
            float ss = __expf(s0-nm)+__expf(s1-nm)+__expf(s2-nm)+__expf(s3-nm);
            ss += __shfl_xor(ss,1); ss += __shfl_xor(ss,2); ss += __shfl_xor(ss,4); ss += __shfl_xor(ss,8);
            l_i[i] = l_i[i]*__expf(m_i[i]-nm) + ss; m_i[i] = nm;
        }
    }
    float inv_l[4];
    #pragma unroll
    for (int i = 0; i < 4; ++i) inv_l[i] = 1.0f / l_i[i];
    float oacc[4][4];
    #pragma unroll
    for (int i = 0; i < 4; ++i) { oacc[i][0]=oacc[i][1]=oacc[i][2]=oacc[i][3]=0.f; }
    for (int kc = 0; kc < 32; ++kc) {
        __syncthreads();
        {
            const int ccr = t >> 2, dblk = (t & 3) * 16;
            const float* src = kb + (size_t)(kc * 64 + ccr) * D_ + dblk;
            #pragma unroll
            for (int qq = 0; qq < 4; ++qq) {
                float4 val = *(const float4*)(src + qq * 4);
                kt[dblk + qq*4 + 0][ccr] = val.x; kt[dblk + qq*4 + 1][ccr] = val.y;
                kt[dblk + qq*4 + 2][ccr] = val.z; kt[dblk + qq*4 + 3][ccr] = val.w;
            }
            const float* srcv = vb + (size_t)(kc * 64 + ccr) * D_ + dblk;
            #pragma unroll
            for (int qq = 0; qq < 4; ++qq)
                *(float4*)&vs[ccr][dblk + qq * 4] = *(const float4*)(srcv + qq * 4);
        }
        __syncthreads();
        float sc[4][4];
        #pragma unroll
        for (int i = 0; i < 4; ++i) { sc[i][0]=sc[i][1]=sc[i][2]=sc[i][3]=0.f; }
        for (int d = 0; d < D_; ++d) {
            const float4 qv = *(const float4*)&qsT[d][r0];
            const float4 kv = *(const float4*)&kt[d][c0];
            #pragma unroll
            for (int i = 0; i < 4; ++i) {
                const float qi = (i==0)?qv.x:(i==1)?qv.y:(i==2)?qv.z:qv.w;
                sc[i][0] = fmaf(qi, kv.x, sc[i][0]); sc[i][1] = fmaf(qi, kv.y, sc[i][1]);
                sc[i][2] = fmaf(qi, kv.z, sc[i][2]); sc[i][3] = fmaf(qi, kv.w, sc[i][3]);
            }
        }
        const int cbase = kc * 64 + c0;
        const uint8_t m0 = mbp[cbase], m1 = mbp[cbase+1], m2 = mbp[cbase+2], m3 = mbp[cbase+3];
        float p[4][4];
        #pragma unroll
        for (int i = 0; i < 4; ++i) {
            const int rglob = row_base + r0 + i;
            const int4 e4 = *(const int4*)(ebp + (size_t)rglob * N_ + cbase);
            float s0 = sc[i][0]*0.125f, s1 = sc[i][1]*0.125f, s2 = sc[i][2]*0.125f, s3 = sc[i][3]*0.125f;
            if (e4.x == 0 || m0) s0 = NEGV; if (e4.y == 0 || m1) s1 = NEGV;
            if (e4.z == 0 || m2) s2 = NEGV; if (e4.w == 0 || m3) s3 = NEGV;
            p[i][0] = __expf(s0-m_i[i])*inv_l[i]; p[i][1] = __expf(s1-m_i[i])*inv_l[i];
            p[i][2] = __expf(s2-m_i[i])*inv_l[i]; p[i][3] = __expf(s3-m_i[i])*inv_l[i];
            *(float4*)&attnb[(size_t)rglob * N_ + cbase] = make_float4(p[i][0],p[i][1],p[i][2],p[i][3]);
        }
        __syncthreads();
        #pragma unroll
        for (int i = 0; i < 4; ++i)
            *(float4*)&kt[r0 + i][c0] = make_float4(p[i][0],p[i][1],p[i][2],p[i][3]);
        __syncthreads();
        for (int c4 = 0; c4 < 64; c4 += 4) {
            float prr[4][4];
            #pragma unroll
            for (int i = 0; i < 4; ++i) {
                const float4 tmp = *(const float4*)&kt[r0 + i][c4];
                prr[i][0]=tmp.x; prr[i][1]=tmp.y; prr[i][2]=tmp.z; prr[i][3]=tmp.w;
            }
            #pragma unroll
            for (int cc = 0; cc < 4; ++cc) {
                const float4 vv = *(const float4*)&vs[c4 + cc][c0];
                #pragma unroll
                for (int i = 0; i < 4; ++i) {
                    oacc[i][0] = fmaf(prr[i][cc], vv.x, oacc[i][0]);
                    oacc[i][1] = fmaf(prr[i][cc], vv.y, oacc[i][1]);
                    oacc[i][2] = fmaf(prr[i][cc], vv.z, oacc[i][2]);
                    oacc[i][3] = fmaf(prr[i][cc], vv.w, oacc[i][3]);
                }
            }
        }
    }
    #pragma unroll
    for (int i = 0; i < 4; ++i)
        *(float4*)&outb[(size_t)(row_base + r0 + i) * D_ + c0] =
            make_float4(oacc[i][0], oacc[i][1], oacc[i][2], oacc[i][3]);
}

extern "C" void kernel_launch(void* const* d_in, const int* in_sizes, int n_in,
                              void* d_out, int out_size, void* d_ws, size_t ws_size,
                              hipStream_t stream) {
    const float* q    = (const float*)d_in[0];
    const float* k    = (const float*)d_in[1];
    const float* v    = (const float*)d_in[2];
    // d_in[3] = k2 (unused by the reference)
    const void*  mraw = d_in[4];
    const int*   edge = (const int*)d_in[5];

    float* out  = (float*)d_out;                         // [16][2048][64]
    float* attn = (float*)d_out + (size_t)BH_ * N_ * D_; // [16][2048][2048]

    char* ws = (char*)d_ws;

    if (ws_size < (size_t)WS_V6) {
        uint8_t* mask_u8 = (uint8_t*)(ws + OFF_MASKU8);
        normalize_mask<<<1, 256, 0, stream>>>(mraw, mask_u8);
        attn_fused<<<dim3(32, 16), 256, 0, stream>>>(q, k, v, mask_u8, edge, out, attn);
        return;
    }

    unsigned long long* mbits = (unsigned long long*)(ws + OFF_MBITS);
    unsigned short*     e16   = (unsigned short*)(ws + OFF_EBITS);
    unsigned short*     qbf   = (unsigned short*)(ws + OFF_QBF);
    unsigned short*     kbf   = (unsigned short*)(ws + OFF_KBF);
    unsigned short*     vT    = (unsigned short*)(ws + OFF_VT);

    prep_all<<<dim3(2576), 256, 0, stream>>>(q, k, v, mraw, edge,
                                             qbf, kbf, vT, e16, mbits);

    if (ws_size >= (size_t)WS_V10) {
        unsigned short* pu = (unsigned short*)(ws + OFF_PU);
        attn_v10<<<dim3(BH_, N_ / 64), 256, 0, stream>>>(
            qbf, kbf, vT, (const unsigned long long*)e16, mbits, pu, out, attn);
    } else {
        attn_v8<<<dim3(BH_, N_ / 64), 256, 0, stream>>>(
            qbf, kbf, vT, (const unsigned long long*)e16, mbits, out, attn);
    }
}

// Round 14
// 125.799 us; speedup vs baseline: 1.4036x; 1.4036x over previous
//
#include <hip/hip_runtime.h>
#include <stdint.h>
#include <math.h>

#define BH_ 16
#define N_  2048
#define D_  64
#define NEGV (-1e15f)

typedef __attribute__((ext_vector_type(8))) short bf16x8;
typedef __attribute__((ext_vector_type(8))) unsigned short us8;
typedef __attribute__((ext_vector_type(4))) float f32x4;

// ---------------- workspace layout ----------------
#define OFF_MASKU8 0u
#define OFF_MBITS  32768u                // 16*32 u64
#define OFF_EBITS  65536u                // 2*2048*128 u16 = 1 MB
#define OFF_QBF    1114112u              // 4 MB bf16
#define OFF_KBF    5308416u              // 4 MB
#define OFF_VT     9502720u              // 4 MB (transposed [bh][d][n])
#define WS_V6      13697024u
#define OFF_PSUM   13697024u             // 16*2048*4 f32 = 512 KB
#define WS_V11     14221312u

// Barrier WITHOUT the implicit vmcnt(0) drain of __syncthreads: LDS visibility
// only (lgkmcnt). Global stores/loads stay in flight across it.
#define BARRIER_LGKM() do {                                   \
    asm volatile("s_waitcnt lgkmcnt(0)" ::: "memory");        \
    __builtin_amdgcn_sched_barrier(0);                        \
    __builtin_amdgcn_s_barrier();                             \
    __builtin_amdgcn_sched_barrier(0);                        \
} while (0)

__device__ __forceinline__ unsigned short f2bf(float f) {
    unsigned u = __float_as_uint(f);
    return (unsigned short)((u + 0x7FFFu + ((u >> 16) & 1u)) >> 16);   // RNE
}

// ---- fused prepass: edge pack (blocks 0..2047), q/k/v convert (2048..2559),
//      mask pack+detect (2560..2575)
__global__ __launch_bounds__(256)
void prep_all(const float* __restrict__ q, const float* __restrict__ k,
              const float* __restrict__ v, const void* __restrict__ mraw,
              const int* __restrict__ edge,
              unsigned short* __restrict__ qbf, unsigned short* __restrict__ kbf,
              unsigned short* __restrict__ vT,
              unsigned short* __restrict__ e16, unsigned long long* __restrict__ mbits)
{
    __shared__ unsigned short shbuf[64][72];
    __shared__ int flag;
    const int bid = blockIdx.x;
    const int t   = threadIdx.x;

    if (bid < 2048) {               // ---- edge -> u16 bitmasks (thread-local)
        const int idx = bid * 256 + t;            // 0..524287
        const int4* p = (const int4*)(edge + (size_t)idx * 16);
        unsigned m = 0;
        #pragma unroll
        for (int i = 0; i < 4; ++i) {
            const int4 vv = p[i];
            m |= (vv.x != 0 ? 1u : 0u) << (i * 4 + 0);
            m |= (vv.y != 0 ? 1u : 0u) << (i * 4 + 1);
            m |= (vv.z != 0 ? 1u : 0u) << (i * 4 + 2);
            m |= (vv.w != 0 ? 1u : 0u) << (i * 4 + 3);
        }
        e16[idx] = (unsigned short)m;
    } else if (bid < 2560) {        // ---- q,k -> bf16; v -> bf16 transposed
        const int b2 = bid - 2048;
        const int rt = b2 & 31, bh = b2 >> 5;
        const size_t base = ((size_t)bh * N_ + (size_t)rt * 64) * D_;
        #pragma unroll
        for (int i = 0; i < 4; ++i) {
            const int idx = t + i * 256;
            float4 f = *(const float4*)(q + base + (size_t)idx * 4);
            ushort4 s; s.x = f2bf(f.x); s.y = f2bf(f.y); s.z = f2bf(f.z); s.w = f2bf(f.w);
            *(ushort4*)(qbf + base + (size_t)idx * 4) = s;
            f = *(const float4*)(k + base + (size_t)idx * 4);
            s.x = f2bf(f.x); s.y = f2bf(f.y); s.z = f2bf(f.z); s.w = f2bf(f.w);
            *(ushort4*)(kbf + base + (size_t)idx * 4) = s;
            f = *(const float4*)(v + base + (size_t)idx * 4);
            const int row = idx >> 4;
            const int d0  = (idx & 15) * 4;
            shbuf[d0 + 0][row] = f2bf(f.x);
            shbuf[d0 + 1][row] = f2bf(f.y);
            shbuf[d0 + 2][row] = f2bf(f.z);
            shbuf[d0 + 3][row] = f2bf(f.w);
        }
        __syncthreads();
        const int d  = t >> 2;
        const int c4 = (t & 3) * 16;
        const size_t ob = ((size_t)bh * D_ + d) * N_ + (size_t)rt * 64 + c4;
        *(us8*)(vT + ob)     = *(us8*)&shbuf[d][c4];
        *(us8*)(vT + ob + 8) = *(us8*)&shbuf[d][c4 + 8];
    } else {                        // ---- mask detect + pack
        const int bh = bid - 2560;
        if (t == 0) flag = 0;
        __syncthreads();
        const int* mi = (const int*)mraw;
        int bad = 0;
        for (int i = t; i < 8192; i += 256)
            if ((unsigned)mi[i] > 1u) bad = 1;
        if (bad) atomicOr(&flag, 1);
        __syncthreads();
        const int is_u8 = flag;
        const uint8_t* m8 = (const uint8_t*)mraw;
        const int w4 = t >> 6, l = t & 63;
        for (int it = 0; it < 8; ++it) {
            const int pos = bh * 2048 + it * 256 + w4 * 64 + l;
            const bool on = is_u8 ? (m8[pos] != 0) : (mi[pos] != 0);
            unsigned long long bal = __ballot(on);
            if (l == 0) mbits[bh * 32 + it * 4 + w4] = bal;
        }
    }
}

// ---- v11 kernel A: partial row sums, 4-way key split (verified round 10).
// Grid (bh, tile, s): bh fastest -> XCD = bh%8. 8192 waves, 16 KB LDS ->
// high occupancy; this phase runs latency-hidden instead of lockstep.
__global__ __launch_bounds__(256)
void attn_sumk(const unsigned short* __restrict__ qbf,
               const unsigned short* __restrict__ kbf,
               const unsigned long long* __restrict__ ebits,
               const unsigned long long* __restrict__ mbits,
               float* __restrict__ psum)
{
    __shared__ unsigned short sK[2][4096];

    const int bh = blockIdx.x, tile = blockIdx.y, s = blockIdx.z;
    const int t = threadIdx.x;
    const int w = t >> 6, lane = t & 63, l15 = lane & 15, lg = lane >> 4;
    const int rbase = tile * 64;
    const int myrow = rbase + w * 16 + l15;
    const int kcb = s * 8;

    const unsigned short* qb = qbf + (size_t)bh * N_ * D_;
    const unsigned short* kb = kbf + (size_t)bh * N_ * D_;
    const unsigned long long* ebrow =
        ebits + ((size_t)(bh & 1) * N_ + (size_t)myrow) * 32;
    const unsigned long long* mb = mbits + bh * 32;

    const bf16x8 aq0 = *(const bf16x8*)(qb + (size_t)myrow * D_ + lg * 8);
    const bf16x8 aq1 = *(const bf16x8*)(qb + (size_t)myrow * D_ + lg * 8 + 32);

    const int s0row = t >> 3, s1row = s0row + 32, t8 = t & 7;
    const int ds0 = s0row * 64 + ((t8 ^ (s0row & 7)) * 8);
    const int ds1 = s1row * 64 + ((t8 ^ (s1row & 7)) * 8);

    {
        const unsigned short* src = kb + (size_t)kcb * 4096;
        *(us8*)(sK[0] + ds0) = *(const us8*)(src + (size_t)t * 8);
        *(us8*)(sK[0] + ds1) = *(const us8*)(src + (size_t)(t + 256) * 8);
        BARRIER_LGKM();
    }
    float lacc = 0.f;
    #pragma unroll 1
    for (int i = 0; i < 8; ++i) {
        const int kc = kcb + i;
        const int cur = i & 1;
        us8 nk0, nk1;
        if (i < 7) {
            const unsigned short* src = kb + (size_t)(kc + 1) * 4096;
            nk0 = *(const us8*)(src + (size_t)t * 8);
            nk1 = *(const us8*)(src + (size_t)(t + 256) * 8);
        }
        const unsigned long long wbits = ebrow[kc] & ~mb[kc];
        const unsigned short* kcur = sK[cur];
        #pragma unroll
        for (int nt = 0; nt < 4; ++nt) {
            const int row = nt * 16 + l15, sw = row & 7;
            const bf16x8 k0 = *(const bf16x8*)(kcur + row * 64 + ((lg ^ sw) * 8));
            const bf16x8 k1 = *(const bf16x8*)(kcur + row * 64 + (((lg + 4) ^ sw) * 8));
            f32x4 c = (f32x4){0.f, 0.f, 0.f, 0.f};
            c = __builtin_amdgcn_mfma_f32_16x16x32_bf16(k0, aq0, c, 0, 0, 0);
            c = __builtin_amdgcn_mfma_f32_16x16x32_bf16(k1, aq1, c, 0, 0, 0);
            const unsigned bits = (unsigned)(wbits >> (nt * 16 + lg * 4)) & 0xFu;
            #pragma unroll
            for (int r = 0; r < 4; ++r)
                lacc += ((bits >> r) & 1u) ? __expf(c[r] * 0.125f) : 0.f;
        }
        if (i < 7) {
            *(us8*)(sK[cur ^ 1] + ds0) = nk0;
            *(us8*)(sK[cur ^ 1] + ds1) = nk1;
        }
        BARRIER_LGKM();
    }
    lacc += __shfl_xor(lacc, 16);
    lacc += __shfl_xor(lacc, 32);
    if (lane < 16) psum[((size_t)bh * N_ + myrow) * 4 + s] = lacc;
}

// ---- v11 kernel B: v8's pass 2 exactly (full 32 chunks, no key split),
// inv read from psum. Grid (bh, tile), bh fastest.
__global__ __launch_bounds__(256)
void attn_pv2(const unsigned short* __restrict__ qbf,
              const unsigned short* __restrict__ kbf,
              const unsigned short* __restrict__ vT,
              const unsigned long long* __restrict__ ebits,
              const unsigned long long* __restrict__ mbits,
              const float* __restrict__ psum,
              float* __restrict__ out, float* __restrict__ attn)
{
    __shared__ unsigned short sK[2][4096];
    __shared__ unsigned short sV[2][4096];
    __shared__ char pbuf[4][2048];

    const int bh   = blockIdx.x;
    const int tile = blockIdx.y;
    const int t    = threadIdx.x;
    const int w    = t >> 6;
    const int lane = t & 63;
    const int l15  = lane & 15;
    const int lg   = lane >> 4;
    const int rbase = tile * 64;
    const int myrow = rbase + w * 16 + l15;

    const unsigned short* qb = qbf + (size_t)bh * N_ * D_;
    const unsigned short* kb = kbf + (size_t)bh * N_ * D_;
    const unsigned short* vb = vT  + (size_t)bh * D_ * N_;
    const unsigned long long* ebrow =
        ebits + ((size_t)(bh & 1) * N_ + (size_t)myrow) * 32;
    const unsigned long long* mb = mbits + bh * 32;
    float* outb = out + (size_t)bh * N_ * D_;
    float* arow = attn + (size_t)bh * N_ * N_ + (size_t)myrow * N_ + lg * 4;

    const f32x4 ps = *(const f32x4*)(psum + ((size_t)bh * N_ + myrow) * 4);
    const float inv = 1.0f / (ps[0] + ps[1] + ps[2] + ps[3]);

    const bf16x8 aq0 = *(const bf16x8*)(qb + (size_t)myrow * D_ + lg * 8);
    const bf16x8 aq1 = *(const bf16x8*)(qb + (size_t)myrow * D_ + lg * 8 + 32);

    const int s0row = t >> 3;
    const int s1row = s0row + 32;
    const int t8    = t & 7;
    const int ds0 = s0row * 64 + ((t8 ^ (s0row & 7)) * 8);
    const int ds1 = s1row * 64 + ((t8 ^ (s1row & 7)) * 8);

    {   // prologue: stage K[0], V[0]
        *(us8*)(sK[0] + ds0) = *(const us8*)(kb + (size_t)t * 8);
        *(us8*)(sK[0] + ds1) = *(const us8*)(kb + (size_t)(t + 256) * 8);
        *(us8*)(sV[0] + ds0) = *(const us8*)(vb + (size_t)s0row * 2048 + t8 * 8);
        *(us8*)(sV[0] + ds1) = *(const us8*)(vb + (size_t)s1row * 2048 + t8 * 8);
        BARRIER_LGKM();
    }

    f32x4 o[4];
    #pragma unroll
    for (int nt = 0; nt < 4; ++nt) o[nt] = (f32x4){0.f, 0.f, 0.f, 0.f};

    char* pbw = pbuf[w];
    const int swzP = (l15 & 7) << 4;
    const int ab0 = (l15 * 128 + lg * 16)      ^ swzP;
    const int ab1 = (l15 * 128 + lg * 16 + 64) ^ swzP;

    #pragma unroll 1
    for (int kc = 0; kc < 32; ++kc) {
        const int cur = kc & 1;
        us8 nk0, nk1, nv0, nv1;
        if (kc < 31) {   // loads issued FIRST (oldest vmem of this chunk)
            const unsigned short* srck = kb + (size_t)(kc + 1) * 4096;
            const unsigned short* srcv = vb + (size_t)(kc + 1) * 64;
            nk0 = *(const us8*)(srck + (size_t)t * 8);
            nk1 = *(const us8*)(srck + (size_t)(t + 256) * 8);
            nv0 = *(const us8*)(srcv + (size_t)s0row * 2048 + t8 * 8);
            nv1 = *(const us8*)(srcv + (size_t)s1row * 2048 + t8 * 8);
        }
        const unsigned long long wbits = ebrow[kc] & ~mb[kc];
        const unsigned short* kcur = sK[cur];
        float4 ev[4];
        #pragma unroll
        for (int nt = 0; nt < 4; ++nt) {
            const int row = nt * 16 + l15, sw = row & 7;
            const bf16x8 k0 = *(const bf16x8*)(kcur + row * 64 + ((lg ^ sw) * 8));
            const bf16x8 k1 = *(const bf16x8*)(kcur + row * 64 + (((lg + 4) ^ sw) * 8));
            f32x4 c = (f32x4){0.f, 0.f, 0.f, 0.f};
            c = __builtin_amdgcn_mfma_f32_16x16x32_bf16(k0, aq0, c, 0, 0, 0);
            c = __builtin_amdgcn_mfma_f32_16x16x32_bf16(k1, aq1, c, 0, 0, 0);
            const unsigned bits = (unsigned)(wbits >> (nt * 16 + lg * 4)) & 0xFu;
            float4 e;
            e.x = (bits & 1u) ? __expf(c[0] * 0.125f) * inv : 0.f;
            e.y = (bits & 2u) ? __expf(c[1] * 0.125f) * inv : 0.f;
            e.z = (bits & 4u) ? __expf(c[2] * 0.125f) * inv : 0.f;
            e.w = (bits & 8u) ? __expf(c[3] * 0.125f) * inv : 0.f;
            ev[nt] = e;
            ushort4 pe;
            pe.x = f2bf(e.x); pe.y = f2bf(e.y); pe.z = f2bf(e.z); pe.w = f2bf(e.w);
            const int wbyte = (l15 * 128 + nt * 32 + lg * 8) ^ swzP;  // XOR last
            *(ushort4*)(pbw + wbyte) = pe;
        }
        const bf16x8 ap0 = *(const bf16x8*)(pbw + ab0);
        const bf16x8 ap1 = *(const bf16x8*)(pbw + ab1);
        const unsigned short* vcur = sV[cur];
        #pragma unroll
        for (int nt = 0; nt < 4; ++nt) {
            const int row = nt * 16 + l15, sw = row & 7;   // d-row
            const bf16x8 bv0 = *(const bf16x8*)(vcur + row * 64 + ((lg ^ sw) * 8));
            const bf16x8 bv1 = *(const bf16x8*)(vcur + row * 64 + (((lg + 4) ^ sw) * 8));
            o[nt] = __builtin_amdgcn_mfma_f32_16x16x32_bf16(ap0, bv0, o[nt], 0, 0, 0);
            o[nt] = __builtin_amdgcn_mfma_f32_16x16x32_bf16(ap1, bv1, o[nt], 0, 0, 0);
        }
        {
            float* astore = arow + kc * 64;
            #pragma unroll
            for (int nt = 0; nt < 4; ++nt)
                *(float4*)(astore + nt * 16) = ev[nt];
        }
        if (kc < 31) {
            *(us8*)(sK[cur ^ 1] + ds0) = nk0;
            *(us8*)(sK[cur ^ 1] + ds1) = nk1;
            *(us8*)(sV[cur ^ 1] + ds0) = nv0;
            *(us8*)(sV[cur ^ 1] + ds1) = nv1;
        }
        BARRIER_LGKM();
    }

    #pragma unroll
    for (int nt = 0; nt < 4; ++nt)
        #pragma unroll
        for (int r = 0; r < 4; ++r)
            outb[(size_t)(rbase + w * 16 + lg * 4 + r) * D_ + nt * 16 + l15] = o[nt][r];
}

// ================= v8 (mid fallback, verified round 11, 121 us) =================
__global__ __launch_bounds__(256)
void attn_v8(const unsigned short* __restrict__ qbf,
             const unsigned short* __restrict__ kbf,
             const unsigned short* __restrict__ vT,
             const unsigned long long* __restrict__ ebits,
             const unsigned long long* __restrict__ mbits,
             float* __restrict__ out, float* __restrict__ attn)
{
    __shared__ unsigned short sK[2][4096];
    __shared__ unsigned short sV[2][4096];
    __shared__ char pbuf[4][2048];

    const int bh   = blockIdx.x;
    const int tile = blockIdx.y;
    const int t    = threadIdx.x;
    const int w    = t >> 6;
    const int lane = t & 63;
    const int l15  = lane & 15;
    const int lg   = lane >> 4;
    const int rbase = tile * 64;
    const int myrow = rbase + w * 16 + l15;

    const unsigned short* qb = qbf + (size_t)bh * N_ * D_;
    const unsigned short* kb = kbf + (size_t)bh * N_ * D_;
    const unsigned short* vb = vT  + (size_t)bh * D_ * N_;
    const unsigned long long* ebrow =
        ebits + ((size_t)(bh & 1) * N_ + (size_t)myrow) * 32;
    const unsigned long long* mb = mbits + bh * 32;
    float* outb = out + (size_t)bh * N_ * D_;
    float* arow = attn + (size_t)bh * N_ * N_ + (size_t)myrow * N_ + lg * 4;

    const bf16x8 aq0 = *(const bf16x8*)(qb + (size_t)myrow * D_ + lg * 8);
    const bf16x8 aq1 = *(const bf16x8*)(qb + (size_t)myrow * D_ + lg * 8 + 32);

    const int s0row = t >> 3;
    const int s1row = s0row + 32;
    const int t8    = t & 7;
    const int ds0 = s0row * 64 + ((t8 ^ (s0row & 7)) * 8);
    const int ds1 = s1row * 64 + ((t8 ^ (s1row & 7)) * 8);

    {
        *(us8*)(sK[0] + ds0) = *(const us8*)(kb + (size_t)t * 8);
        *(us8*)(sK[0] + ds1) = *(const us8*)(kb + (size_t)(t + 256) * 8);
        BARRIER_LGKM();
    }
    float lacc = 0.f;
    #pragma unroll 1
    for (int kc = 0; kc < 32; ++kc) {
        const int cur = kc & 1;
        us8 nk0, nk1;
        if (kc < 31) {
            const unsigned short* s = kb + (size_t)(kc + 1) * 4096;
            nk0 = *(const us8*)(s + (size_t)t * 8);
            nk1 = *(const us8*)(s + (size_t)(t + 256) * 8);
        }
        const unsigned long long wbits = ebrow[kc] & ~mb[kc];
        const unsigned short* kcur = sK[cur];
        #pragma unroll
        for (int nt = 0; nt < 4; ++nt) {
            const int row = nt * 16 + l15, sw = row & 7;
            const bf16x8 k0 = *(const bf16x8*)(kcur + row * 64 + ((lg ^ sw) * 8));
            const bf16x8 k1 = *(const bf16x8*)(kcur + row * 64 + (((lg + 4) ^ sw) * 8));
            f32x4 c = (f32x4){0.f, 0.f, 0.f, 0.f};
            c = __builtin_amdgcn_mfma_f32_16x16x32_bf16(k0, aq0, c, 0, 0, 0);
            c = __builtin_amdgcn_mfma_f32_16x16x32_bf16(k1, aq1, c, 0, 0, 0);
            const unsigned bits = (unsigned)(wbits >> (nt * 16 + lg * 4)) & 0xFu;
            #pragma unroll
            for (int r = 0; r < 4; ++r)
                lacc += ((bits >> r) & 1u) ? __expf(c[r] * 0.125f) : 0.f;
        }
        if (kc < 31) {
            *(us8*)(sK[cur ^ 1] + ds0) = nk0;
            *(us8*)(sK[cur ^ 1] + ds1) = nk1;
        }
        BARRIER_LGKM();
    }
    lacc += __shfl_xor(lacc, 16);
    lacc += __shfl_xor(lacc, 32);
    const float inv = 1.0f / lacc;

    {
        *(us8*)(sK[0] + ds0) = *(const us8*)(kb + (size_t)t * 8);
        *(us8*)(sK[0] + ds1) = *(const us8*)(kb + (size_t)(t + 256) * 8);
        *(us8*)(sV[0] + ds0) = *(const us8*)(vb + (size_t)s0row * 2048 + t8 * 8);
        *(us8*)(sV[0] + ds1) = *(const us8*)(vb + (size_t)s1row * 2048 + t8 * 8);
        BARRIER_LGKM();
    }

    f32x4 o[4];
    #pragma unroll
    for (int nt = 0; nt < 4; ++nt) o[nt] = (f32x4){0.f, 0.f, 0.f, 0.f};

    char* pbw = pbuf[w];
    const int swzP = (l15 & 7) << 4;
    const int ab0 = (l15 * 128 + lg * 16)      ^ swzP;
    const int ab1 = (l15 * 128 + lg * 16 + 64) ^ swzP;

    #pragma unroll 1
    for (int kc = 0; kc < 32; ++kc) {
        const int cur = kc & 1;
        us8 nk0, nk1, nv0, nv1;
        if (kc < 31) {
            const unsigned short* srck = kb + (size_t)(kc + 1) * 4096;
            const unsigned short* srcv = vb + (size_t)(kc + 1) * 64;
            nk0 = *(const us8*)(srck + (size_t)t * 8);
            nk1 = *(const us8*)(srck + (size_t)(t + 256) * 8);
            nv0 = *(const us8*)(srcv + (size_t)s0row * 2048 + t8 * 8);
            nv1 = *(const us8*)(srcv + (size_t)s1row * 2048 + t8 * 8);
        }
        const unsigned long long wbits = ebrow[kc] & ~mb[kc];
        const unsigned short* kcur = sK[cur];
        float4 ev[4];
        #pragma unroll
        for (int nt = 0; nt < 4; ++nt) {
            const int row = nt * 16 + l15, sw = row & 7;
            const bf16x8 k0 = *(const bf16x8*)(kcur + row * 64 + ((lg ^ sw) * 8));
            const bf16x8 k1 = *(const bf16x8*)(kcur + row * 64 + (((lg + 4) ^ sw) * 8));
            f32x4 c = (f32x4){0.f, 0.f, 0.f, 0.f};
            c = __builtin_amdgcn_mfma_f32_16x16x32_bf16(k0, aq0, c, 0, 0, 0);
            c = __builtin_amdgcn_mfma_f32_16x16x32_bf16(k1, aq1, c, 0, 0, 0);
            const unsigned bits = (unsigned)(wbits >> (nt * 16 + lg * 4)) & 0xFu;
            float4 e;
            e.x = (bits & 1u) ? __expf(c[0] * 0.125f) * inv : 0.f;
            e.y = (bits & 2u) ? __expf(c[1] * 0.125f) * inv : 0.f;
            e.z = (bits & 4u) ? __expf(c[2] * 0.125f) * inv : 0.f;
            e.w = (bits & 8u) ? __expf(c[3] * 0.125f) * inv : 0.f;
            ev[nt] = e;
            ushort4 pe;
            pe.x = f2bf(e.x); pe.y = f2bf(e.y); pe.z = f2bf(e.z); pe.w = f2bf(e.w);
            const int wbyte = (l15 * 128 + nt * 32 + lg * 8) ^ swzP;
            *(ushort4*)(pbw + wbyte) = pe;
        }
        const bf16x8 ap0 = *(const bf16x8*)(pbw + ab0);
        const bf16x8 ap1 = *(const bf16x8*)(pbw + ab1);
        const unsigned short* vcur = sV[cur];
        #pragma unroll
        for (int nt = 0; nt < 4; ++nt) {
            const int row = nt * 16 + l15, sw = row & 7;
            const bf16x8 bv0 = *(const bf16x8*)(vcur + row * 64 + ((lg ^ sw) * 8));
            const bf16x8 bv1 = *(const bf16x8*)(vcur + row * 64 + (((lg + 4) ^ sw) * 8));
            o[nt] = __builtin_amdgcn_mfma_f32_16x16x32_bf16(ap0, bv0, o[nt], 0, 0, 0);
            o[nt] = __builtin_amdgcn_mfma_f32_16x16x32_bf16(ap1, bv1, o[nt], 0, 0, 0);
        }
        {
            float* astore = arow + kc * 64;
            #pragma unroll
            for (int nt = 0; nt < 4; ++nt)
                *(float4*)(astore + nt * 16) = ev[nt];
        }
        if (kc < 31) {
            *(us8*)(sK[cur ^ 1] + ds0) = nk0;
            *(us8*)(sK[cur ^ 1] + ds1) = nk1;
            *(us8*)(sV[cur ^ 1] + ds0) = nv0;
            *(us8*)(sV[cur ^ 1] + ds1) = nv1;
        }
        BARRIER_LGKM();
    }

    #pragma unroll
    for (int nt = 0; nt < 4; ++nt)
        #pragma unroll
        for (int r = 0; r < 4; ++r)
            outb[(size_t)(rbase + w * 16 + lg * 4 + r) * D_ + nt * 16 + l15] = o[nt][r];
}

// ================= fp32 deep fallback (needs only 32 KB ws) =================
__global__ __launch_bounds__(256)
void normalize_mask(const void* __restrict__ mask_raw, uint8_t* __restrict__ mask_out)
{
    __shared__ int is_u8;
    const int t = threadIdx.x;
    if (t == 0) is_u8 = 0;
    __syncthreads();
    const int* mi = (const int*)mask_raw;
    int bad = 0;
    for (int i = t; i < 8192; i += 256)
        if ((unsigned)mi[i] > 1u) bad = 1;
    if (bad) atomicOr(&is_u8, 1);
    __syncthreads();
    const int total = BH_ * N_;
    if (is_u8) {
        const uint8_t* m8 = (const uint8_t*)mask_raw;
        for (int i = t; i < total; i += 256) mask_out[i] = m8[i] ? 1 : 0;
    } else {
        for (int i = t; i < total; i += 256) mask_out[i] = (uint8_t)mi[i];
    }
}

__global__ __launch_bounds__(256)
void attn_fused(const float* __restrict__ q, const float* __restrict__ k,
                const float* __restrict__ v, const uint8_t* __restrict__ mask,
                const int* __restrict__ edge, float* __restrict__ out,
                float* __restrict__ attn)
{
    __shared__ float qsT[D_][64 + 4];
    __shared__ float kt [D_][64 + 4];
    __shared__ float vs [64][D_ + 4];
    const int tile = blockIdx.x, bh = blockIdx.y, t = threadIdx.x;
    const int rg = t >> 4, cg = t & 15, r0 = rg * 4, c0 = cg * 4;
    const int row_base = tile * 64;
    const float* qb = q + (size_t)bh * N_ * D_;
    const float* kb = k + (size_t)bh * N_ * D_;
    const float* vb = v + (size_t)bh * N_ * D_;
    const uint8_t* mbp = mask + (size_t)bh * N_;
    const int* ebp = edge + (size_t)(bh & 1) * N_ * N_;
    float* outb = out + (size_t)bh * N_ * D_;
    float* attnb = attn + (size_t)bh * N_ * N_;
    {
        const int rr = t >> 2, dblk = (t & 3) * 16;
        const float* src = qb + (size_t)(row_base + rr) * D_ + dblk;
        #pragma unroll
        for (int qq = 0; qq < 4; ++qq) {
            float4 val = *(const float4*)(src + qq * 4);
            qsT[dblk + qq*4 + 0][rr] = val.x; qsT[dblk + qq*4 + 1][rr] = val.y;
            qsT[dblk + qq*4 + 2][rr] = val.z; qsT[dblk + qq*4 + 3][rr] = val.w;
        }
    }
    float m_i[4], l_i[4];
    #pragma unroll
    for (int i = 0; i < 4; ++i) { m_i[i] = -INFINITY; l_i[i] = 0.f; }
    for (int kc = 0; kc < 32; ++kc) {
        __syncthreads();
        {
            const int ccr = t >> 2, dblk = (t & 3) * 16;
            const float* src = kb + (size_t)(kc * 64 + ccr) * D_ + dblk;
            #pragma unroll
            for (int qq = 0; qq < 4; ++qq) {
                float4 val = *(const float4*)(src + qq * 4);
                kt[dblk + qq*4 + 0][ccr] = val.x; kt[dblk + qq*4 + 1][ccr] = val.y;
                kt[dblk + qq*4 + 2][ccr] = val.z; kt[dblk + qq*4 + 3][ccr] = val.w;
            }
        }
        __syncthreads();
        float sc[4][4];
        #pragma unroll
        for (int i = 0; i < 4; ++i) { sc[i][0]=sc[i][1]=sc[i][2]=sc[i][3]=0.f; }
        for (int d = 0; d < D_; ++d) {
            const float4 qv = *(const float4*)&qsT[d][r0];
            const float4 kv = *(const float4*)&kt[d][c0];
            #pragma unroll
            for (int i = 0; i < 4; ++i) {
                const float qi = (i==0)?qv.x:(i==1)?qv.y:(i==2)?qv.z:qv.w;
                sc[i][0] = fmaf(qi, kv.x, sc[i][0]); sc[i][1] = fmaf(qi, kv.y, sc[i][1]);
                sc[i][2] = fmaf(qi, kv.z, sc[i][2]); sc[i][3] = fmaf(qi, kv.w, sc[i][3]);
            }
        }
        const int cbase = kc * 64 + c0;
        const uint8_t m0 = mbp[cbase], m1 = mbp[cbase+1], m2 = mbp[cbase+2], m3 = mbp[cbase+3];
        #pragma unroll
        for (int i = 0; i < 4; ++i) {
            const int rglob = row_base + r0 + i;
            const int4 e4 = *(const int4*)(ebp + (size_t)rglob * N_ + cbase);
            float s0 = sc[i][0]*0.125f, s1 = sc[i][1]*0.125f, s2 = sc[i][2]*0.125f, s3 = sc[i][3]*0.125f;
            if (e4.x == 0 || m0) s0 = NEGV; if (e4.y == 0 || m1) s1 = NEGV;
            if (e4.z == 0 || m2) s2 = NEGV; if (e4.w == 0 || m3) s3 = NEGV;
            float cmax = fmaxf(fmaxf(s0,s1), fmaxf(s2,s3));
            cmax = fmaxf(cmax, __shfl_xor(cmax,1)); cmax = fmaxf(cmax, __shfl_xor(cmax,2));
            cmax = fmaxf(cmax, __shfl_xor(cmax,4)); cmax = fmaxf(cmax, __shfl_xor(cmax,8));
            const float nm = fmaxf(m_i[i], cmax);
            float ss = __expf(s0-nm)+__expf(s1-nm)+__expf(s2-nm)+__expf(s3-nm);
            ss += __shfl_xor(ss,1); ss += __shfl_xor(ss,2); ss += __shfl_xor(ss,4); ss += __shfl_xor(ss,8);
            l_i[i] = l_i[i]*__expf(m_i[i]-nm) + ss; m_i[i] = nm;
        }
    }
    float inv_l[4];
    #pragma unroll
    for (int i = 0; i < 4; ++i) inv_l[i] = 1.0f / l_i[i];
    float oacc[4][4];
    #pragma unroll
    for (int i = 0; i < 4; ++i) { oacc[i][0]=oacc[i][1]=oacc[i][2]=oacc[i][3]=0.f; }
    for (int kc = 0; kc < 32; ++kc) {
        __syncthreads();
        {
            const int ccr = t >> 2, dblk = (t & 3) * 16;
            const float* src = kb + (size_t)(kc * 64 + ccr) * D_ + dblk;
            #pragma unroll
            for (int qq = 0; qq < 4; ++qq) {
                float4 val = *(const float4*)(src + qq * 4);
                kt[dblk + qq*4 + 0][ccr] = val.x; kt[dblk + qq*4 + 1][ccr] = val.y;
                kt[dblk + qq*4 + 2][ccr] = val.z; kt[dblk + qq*4 + 3][ccr] = val.w;
            }
            const float* srcv = vb + (size_t)(kc * 64 + ccr) * D_ + dblk;
            #pragma unroll
            for (int qq = 0; qq < 4; ++qq)
                *(float4*)&vs[ccr][dblk + qq * 4] = *(const float4*)(srcv + qq * 4);
        }
        __syncthreads();
        float sc[4][4];
        #pragma unroll
        for (int i = 0; i < 4; ++i) { sc[i][0]=sc[i][1]=sc[i][2]=sc[i][3]=0.f; }
        for (int d = 0; d < D_; ++d) {
            const float4 qv = *(const float4*)&qsT[d][r0];
            const float4 kv = *(const float4*)&kt[d][c0];
            #pragma unroll
            for (int i = 0; i < 4; ++i) {
                const float qi = (i==0)?qv.x:(i==1)?qv.y:(i==2)?qv.z:qv.w;
                sc[i][0] = fmaf(qi, kv.x, sc[i][0]); sc[i][1] = fmaf(qi, kv.y, sc[i][1]);
                sc[i][2] = fmaf(qi, kv.z, sc[i][2]); sc[i][3] = fmaf(qi, kv.w, sc[i][3]);
            }
        }
        const int cbase = kc * 64 + c0;
        const uint8_t m0 = mbp[cbase], m1 = mbp[cbase+1], m2 = mbp[cbase+2], m3 = mbp[cbase+3];
        float p[4][4];
        #pragma unroll
        for (int i = 0; i < 4; ++i) {
            const int rglob = row_base + r0 + i;
            const int4 e4 = *(const int4*)(ebp + (size_t)rglob * N_ + cbase);
            float s0 = sc[i][0]*0.125f, s1 = sc[i][1]*0.125f, s2 = sc[i][2]*0.125f, s3 = sc[i][3]*0.125f;
            if (e4.x == 0 || m0) s0 = NEGV; if (e4.y == 0 || m1) s1 = NEGV;
            if (e4.z == 0 || m2) s2 = NEGV; if (e4.w == 0 || m3) s3 = NEGV;
            p[i][0] = __expf(s0-m_i[i])*inv_l[i]; p[i][1] = __expf(s1-m_i[i])*inv_l[i];
            p[i][2] = __expf(s2-m_i[i])*inv_l[i]; p[i][3] = __expf(s3-m_i[i])*inv_l[i];
            *(float4*)&attnb[(size_t)rglob * N_ + cbase] = make_float4(p[i][0],p[i][1],p[i][2],p[i][3]);
        }
        __syncthreads();
        #pragma unroll
        for (int i = 0; i < 4; ++i)
            *(float4*)&kt[r0 + i][c0] = make_float4(p[i][0],p[i][1],p[i][2],p[i][3]);
        __syncthreads();
        for (int c4 = 0; c4 < 64; c4 += 4) {
            float prr[4][4];
            #pragma unroll
            for (int i = 0; i < 4; ++i) {
                const float4 tmp = *(const float4*)&kt[r0 + i][c4];
                prr[i][0]=tmp.x; prr[i][1]=tmp.y; prr[i][2]=tmp.z; prr[i][3]=tmp.w;
            }
            #pragma unroll
            for (int cc = 0; cc < 4; ++cc) {
                const float4 vv = *(const float4*)&vs[c4 + cc][c0];
                #pragma unroll
                for (int i = 0; i < 4; ++i) {
                    oacc[i][0] = fmaf(prr[i][cc], vv.x, oacc[i][0]);
                    oacc[i][1] = fmaf(prr[i][cc], vv.y, oacc[i][1]);
                    oacc[i][2] = fmaf(prr[i][cc], vv.z, oacc[i][2]);
                    oacc[i][3] = fmaf(prr[i][cc], vv.w, oacc[i][3]);
                }
            }
        }
    }
    #pragma unroll
    for (int i = 0; i < 4; ++i)
        *(float4*)&outb[(size_t)(row_base + r0 + i) * D_ + c0] =
            make_float4(oacc[i][0], oacc[i][1], oacc[i][2], oacc[i][3]);
}

extern "C" void kernel_launch(void* const* d_in, const int* in_sizes, int n_in,
                              void* d_out, int out_size, void* d_ws, size_t ws_size,
                              hipStream_t stream) {
    const float* q    = (const float*)d_in[0];
    const float* k    = (const float*)d_in[1];
    const float* v    = (const float*)d_in[2];
    // d_in[3] = k2 (unused by the reference)
    const void*  mraw = d_in[4];
    const int*   edge = (const int*)d_in[5];

    float* out  = (float*)d_out;                         // [16][2048][64]
    float* attn = (float*)d_out + (size_t)BH_ * N_ * D_; // [16][2048][2048]

    char* ws = (char*)d_ws;

    if (ws_size < (size_t)WS_V6) {
        uint8_t* mask_u8 = (uint8_t*)(ws + OFF_MASKU8);
        normalize_mask<<<1, 256, 0, stream>>>(mraw, mask_u8);
        attn_fused<<<dim3(32, 16), 256, 0, stream>>>(q, k, v, mask_u8, edge, out, attn);
        return;
    }

    unsigned long long* mbits = (unsigned long long*)(ws + OFF_MBITS);
    unsigned short*     e16   = (unsigned short*)(ws + OFF_EBITS);
    unsigned short*     qbf   = (unsigned short*)(ws + OFF_QBF);
    unsigned short*     kbf   = (unsigned short*)(ws + OFF_KBF);
    unsigned short*     vT    = (unsigned short*)(ws + OFF_VT);

    prep_all<<<dim3(2576), 256, 0, stream>>>(q, k, v, mraw, edge,
                                             qbf, kbf, vT, e16, mbits);

    if (ws_size >= (size_t)WS_V11) {
        float* psum = (float*)(ws + OFF_PSUM);
        attn_sumk<<<dim3(BH_, 32, 4), 256, 0, stream>>>(
            qbf, kbf, (const unsigned long long*)e16, mbits, psum);
        attn_pv2<<<dim3(BH_, 32), 256, 0, stream>>>(
            qbf, kbf, vT, (const unsigned long long*)e16, mbits, psum, out, attn);
    } else {
        attn_v8<<<dim3(BH_, N_ / 64), 256, 0, stream>>>(
            qbf, kbf, vT, (const unsigned long long*)e16, mbits, out, attn);
    }
}

// Round 15
// 121.720 us; speedup vs baseline: 1.4507x; 1.0335x over previous
//
#include <hip/hip_runtime.h>
#include <stdint.h>
#include <math.h>

#define BH_ 16
#define N_  2048
#define D_  64
#define NEGV (-1e15f)

typedef __attribute__((ext_vector_type(8))) short bf16x8;
typedef __attribute__((ext_vector_type(8))) unsigned short us8;
typedef __attribute__((ext_vector_type(4))) float f32x4;

// ---------------- workspace layout ----------------
#define OFF_MASKU8 0u
#define OFF_MBITS  32768u                // 16*32 u64
#define OFF_EBITS  65536u                // 2*2048*128 u16 = 1 MB
#define OFF_QBF    1114112u              // 4 MB bf16
#define OFF_KBF    5308416u              // 4 MB
#define OFF_VT     9502720u              // 4 MB (transposed [bh][d][n])
#define WS_V6      13697024u

// Barrier WITHOUT the implicit vmcnt(0) drain of __syncthreads: LDS visibility
// only (lgkmcnt). Global stores/loads stay in flight across it.
#define BARRIER_LGKM() do {                                   \
    asm volatile("s_waitcnt lgkmcnt(0)" ::: "memory");        \
    __builtin_amdgcn_sched_barrier(0);                        \
    __builtin_amdgcn_s_barrier();                             \
    __builtin_amdgcn_sched_barrier(0);                        \
} while (0)

__device__ __forceinline__ unsigned short f2bf(float f) {
    unsigned u = __float_as_uint(f);
    return (unsigned short)((u + 0x7FFFu + ((u >> 16) & 1u)) >> 16);   // RNE
}

// ---- fused prepass: edge pack (blocks 0..2047), q/k/v convert (2048..2559),
//      mask pack+detect (2560..2575)
__global__ __launch_bounds__(256)
void prep_all(const float* __restrict__ q, const float* __restrict__ k,
              const float* __restrict__ v, const void* __restrict__ mraw,
              const int* __restrict__ edge,
              unsigned short* __restrict__ qbf, unsigned short* __restrict__ kbf,
              unsigned short* __restrict__ vT,
              unsigned short* __restrict__ e16, unsigned long long* __restrict__ mbits)
{
    __shared__ unsigned short shbuf[64][72];
    __shared__ int flag;
    const int bid = blockIdx.x;
    const int t   = threadIdx.x;

    if (bid < 2048) {               // ---- edge -> u16 bitmasks (thread-local)
        const int idx = bid * 256 + t;            // 0..524287
        const int4* p = (const int4*)(edge + (size_t)idx * 16);
        unsigned m = 0;
        #pragma unroll
        for (int i = 0; i < 4; ++i) {
            const int4 vv = p[i];
            m |= (vv.x != 0 ? 1u : 0u) << (i * 4 + 0);
            m |= (vv.y != 0 ? 1u : 0u) << (i * 4 + 1);
            m |= (vv.z != 0 ? 1u : 0u) << (i * 4 + 2);
            m |= (vv.w != 0 ? 1u : 0u) << (i * 4 + 3);
        }
        e16[idx] = (unsigned short)m;
    } else if (bid < 2560) {        // ---- q,k -> bf16; v -> bf16 transposed
        const int b2 = bid - 2048;
        const int rt = b2 & 31, bh = b2 >> 5;
        const size_t base = ((size_t)bh * N_ + (size_t)rt * 64) * D_;
        #pragma unroll
        for (int i = 0; i < 4; ++i) {
            const int idx = t + i * 256;
            float4 f = *(const float4*)(q + base + (size_t)idx * 4);
            ushort4 s; s.x = f2bf(f.x); s.y = f2bf(f.y); s.z = f2bf(f.z); s.w = f2bf(f.w);
            *(ushort4*)(qbf + base + (size_t)idx * 4) = s;
            f = *(const float4*)(k + base + (size_t)idx * 4);
            s.x = f2bf(f.x); s.y = f2bf(f.y); s.z = f2bf(f.z); s.w = f2bf(f.w);
            *(ushort4*)(kbf + base + (size_t)idx * 4) = s;
            f = *(const float4*)(v + base + (size_t)idx * 4);
            const int row = idx >> 4;
            const int d0  = (idx & 15) * 4;
            shbuf[d0 + 0][row] = f2bf(f.x);
            shbuf[d0 + 1][row] = f2bf(f.y);
            shbuf[d0 + 2][row] = f2bf(f.z);
            shbuf[d0 + 3][row] = f2bf(f.w);
        }
        __syncthreads();
        const int d  = t >> 2;
        const int c4 = (t & 3) * 16;
        const size_t ob = ((size_t)bh * D_ + d) * N_ + (size_t)rt * 64 + c4;
        *(us8*)(vT + ob)     = *(us8*)&shbuf[d][c4];
        *(us8*)(vT + ob + 8) = *(us8*)&shbuf[d][c4 + 8];
    } else {                        // ---- mask detect + pack
        const int bh = bid - 2560;
        if (t == 0) flag = 0;
        __syncthreads();
        const int* mi = (const int*)mraw;
        int bad = 0;
        for (int i = t; i < 8192; i += 256)
            if ((unsigned)mi[i] > 1u) bad = 1;
        if (bad) atomicOr(&flag, 1);
        __syncthreads();
        const int is_u8 = flag;
        const uint8_t* m8 = (const uint8_t*)mraw;
        const int w4 = t >> 6, l = t & 63;
        for (int it = 0; it < 8; ++it) {
            const int pos = bh * 2048 + it * 256 + w4 * 64 + l;
            const bool on = is_u8 ? (m8[pos] != 0) : (mi[pos] != 0);
            unsigned long long bal = __ballot(on);
            if (l == 0) mbits[bh * 32 + it * 4 + w4] = bal;
        }
    }
}

// ---- main v12 = v8 with a 2-chunk barrier interval: pair-buffers of 2 key
// chunks, half the barriers (~66 vs ~130), 2x independent work per interval
// for the scheduler to overlap staging latency. Everything else identical.
__global__ __launch_bounds__(256)
void attn_v12(const unsigned short* __restrict__ qbf,
              const unsigned short* __restrict__ kbf,
              const unsigned short* __restrict__ vT,
              const unsigned long long* __restrict__ ebits,
              const unsigned long long* __restrict__ mbits,
              float* __restrict__ out, float* __restrict__ attn)
{
    __shared__ unsigned short sK2[2][8192];  // 2 chunks (64 keys x 64 d) per buffer
    __shared__ unsigned short sV2[2][8192];
    __shared__ char pbuf[4][2048];           // per-wave 16x64 bf16 P tile

    const int bh   = blockIdx.x;    // FASTEST -> XCD = bh % 8 (T1 locality)
    const int tile = blockIdx.y;    // 0..31
    const int t    = threadIdx.x;
    const int w    = t >> 6;
    const int lane = t & 63;
    const int l15  = lane & 15;
    const int lg   = lane >> 4;
    const int rbase = tile * 64;
    const int myrow = rbase + w * 16 + l15;

    const unsigned short* qb = qbf + (size_t)bh * N_ * D_;
    const unsigned short* kb = kbf + (size_t)bh * N_ * D_;
    const unsigned short* vb = vT  + (size_t)bh * D_ * N_;
    const unsigned long long* ebrow =
        ebits + ((size_t)(bh & 1) * N_ + (size_t)myrow) * 32;
    const unsigned long long* mb = mbits + bh * 32;
    float* outb = out + (size_t)bh * N_ * D_;
    float* arow = attn + (size_t)bh * N_ * N_ + (size_t)myrow * N_ + lg * 4;

    // Q fragments (B-operand of swapped QK^T), row = myrow
    const bf16x8 aq0 = *(const bf16x8*)(qb + (size_t)myrow * D_ + lg * 8);
    const bf16x8 aq1 = *(const bf16x8*)(qb + (size_t)myrow * D_ + lg * 8 + 32);

    // cooperative staging: thread t covers 16B slots t and t+256 of each 8KB chunk
    const int s0row = t >> 3;               // 0..31
    const int s1row = s0row + 32;           // 32..63
    const int t8    = t & 7;
    const int ds0 = s0row * 64 + ((t8 ^ (s0row & 7)) * 8);
    const int ds1 = s1row * 64 + ((t8 ^ (s1row & 7)) * 8);

    // =============== PASS 1: row sums of exp (K only) ===============
    {   // stage interval 0 (chunks 0,1)
        *(us8*)(sK2[0] + ds0)        = *(const us8*)(kb + (size_t)t * 8);
        *(us8*)(sK2[0] + ds1)        = *(const us8*)(kb + (size_t)(t + 256) * 8);
        *(us8*)(sK2[0] + 4096 + ds0) = *(const us8*)(kb + 4096 + (size_t)t * 8);
        *(us8*)(sK2[0] + 4096 + ds1) = *(const us8*)(kb + 4096 + (size_t)(t + 256) * 8);
        BARRIER_LGKM();
    }
    float lacc = 0.f;
    #pragma unroll 1
    for (int iv = 0; iv < 16; ++iv) {
        const int cur = iv & 1;
        us8 nk[4];
        if (iv < 15) {   // prefetch next interval (2 chunks)
            const unsigned short* s = kb + (size_t)(2 * iv + 2) * 4096;
            nk[0] = *(const us8*)(s + (size_t)t * 8);
            nk[1] = *(const us8*)(s + (size_t)(t + 256) * 8);
            nk[2] = *(const us8*)(s + 4096 + (size_t)t * 8);
            nk[3] = *(const us8*)(s + 4096 + (size_t)(t + 256) * 8);
        }
        #pragma unroll
        for (int sub = 0; sub < 2; ++sub) {
            const int kc = 2 * iv + sub;
            const unsigned long long wbits = ebrow[kc] & ~mb[kc];
            const unsigned short* kcur = sK2[cur] + sub * 4096;
            #pragma unroll
            for (int nt = 0; nt < 4; ++nt) {
                const int row = nt * 16 + l15, sw = row & 7;
                const bf16x8 k0 = *(const bf16x8*)(kcur + row * 64 + ((lg ^ sw) * 8));
                const bf16x8 k1 = *(const bf16x8*)(kcur + row * 64 + (((lg + 4) ^ sw) * 8));
                f32x4 c = (f32x4){0.f, 0.f, 0.f, 0.f};
                c = __builtin_amdgcn_mfma_f32_16x16x32_bf16(k0, aq0, c, 0, 0, 0);
                c = __builtin_amdgcn_mfma_f32_16x16x32_bf16(k1, aq1, c, 0, 0, 0);
                const unsigned bits = (unsigned)(wbits >> (nt * 16 + lg * 4)) & 0xFu;
                #pragma unroll
                for (int r = 0; r < 4; ++r)
                    lacc += ((bits >> r) & 1u) ? __expf(c[r] * 0.125f) : 0.f;
            }
        }
        if (iv < 15) {
            unsigned short* kn = sK2[cur ^ 1];
            *(us8*)(kn + ds0)        = nk[0];
            *(us8*)(kn + ds1)        = nk[1];
            *(us8*)(kn + 4096 + ds0) = nk[2];
            *(us8*)(kn + 4096 + ds1) = nk[3];
        }
        BARRIER_LGKM();
    }
    lacc += __shfl_xor(lacc, 16);
    lacc += __shfl_xor(lacc, 32);
    const float inv = 1.0f / lacc;     // full row sum (row myrow)

    // =============== PASS 2: recompute, store attn, PV ===============
    {   // prologue: stage interval 0 for K and V
        *(us8*)(sK2[0] + ds0)        = *(const us8*)(kb + (size_t)t * 8);
        *(us8*)(sK2[0] + ds1)        = *(const us8*)(kb + (size_t)(t + 256) * 8);
        *(us8*)(sK2[0] + 4096 + ds0) = *(const us8*)(kb + 4096 + (size_t)t * 8);
        *(us8*)(sK2[0] + 4096 + ds1) = *(const us8*)(kb + 4096 + (size_t)(t + 256) * 8);
        *(us8*)(sV2[0] + ds0)        = *(const us8*)(vb + (size_t)s0row * 2048 + t8 * 8);
        *(us8*)(sV2[0] + ds1)        = *(const us8*)(vb + (size_t)s1row * 2048 + t8 * 8);
        *(us8*)(sV2[0] + 4096 + ds0) = *(const us8*)(vb + 64 + (size_t)s0row * 2048 + t8 * 8);
        *(us8*)(sV2[0] + 4096 + ds1) = *(const us8*)(vb + 64 + (size_t)s1row * 2048 + t8 * 8);
        BARRIER_LGKM();
    }

    f32x4 o[4];
    #pragma unroll
    for (int nt = 0; nt < 4; ++nt) o[nt] = (f32x4){0.f, 0.f, 0.f, 0.f};

    char* pbw = pbuf[w];
    const int swzP = (l15 & 7) << 4;
    const int ab0 = (l15 * 128 + lg * 16)      ^ swzP;
    const int ab1 = (l15 * 128 + lg * 16 + 64) ^ swzP;

    #pragma unroll 1
    for (int iv = 0; iv < 16; ++iv) {
        const int cur = iv & 1;
        us8 nk[4], nv[4];
        if (iv < 15) {   // prefetch next interval's K and V (oldest vmem)
            const unsigned short* srck = kb + (size_t)(2 * iv + 2) * 4096;
            const unsigned short* srcv = vb + (size_t)(2 * iv + 2) * 64;
            nk[0] = *(const us8*)(srck + (size_t)t * 8);
            nk[1] = *(const us8*)(srck + (size_t)(t + 256) * 8);
            nk[2] = *(const us8*)(srck + 4096 + (size_t)t * 8);
            nk[3] = *(const us8*)(srck + 4096 + (size_t)(t + 256) * 8);
            nv[0] = *(const us8*)(srcv + (size_t)s0row * 2048 + t8 * 8);
            nv[1] = *(const us8*)(srcv + (size_t)s1row * 2048 + t8 * 8);
            nv[2] = *(const us8*)(srcv + 64 + (size_t)s0row * 2048 + t8 * 8);
            nv[3] = *(const us8*)(srcv + 64 + (size_t)s1row * 2048 + t8 * 8);
        }
        #pragma unroll
        for (int sub = 0; sub < 2; ++sub) {
            const int kc = 2 * iv + sub;
            const unsigned long long wbits = ebrow[kc] & ~mb[kc];
            const unsigned short* kcur = sK2[cur] + sub * 4096;
            float4 ev[4];
            #pragma unroll
            for (int nt = 0; nt < 4; ++nt) {
                const int row = nt * 16 + l15, sw = row & 7;
                const bf16x8 k0 = *(const bf16x8*)(kcur + row * 64 + ((lg ^ sw) * 8));
                const bf16x8 k1 = *(const bf16x8*)(kcur + row * 64 + (((lg + 4) ^ sw) * 8));
                f32x4 c = (f32x4){0.f, 0.f, 0.f, 0.f};
                c = __builtin_amdgcn_mfma_f32_16x16x32_bf16(k0, aq0, c, 0, 0, 0);
                c = __builtin_amdgcn_mfma_f32_16x16x32_bf16(k1, aq1, c, 0, 0, 0);
                const unsigned bits = (unsigned)(wbits >> (nt * 16 + lg * 4)) & 0xFu;
                float4 e;
                e.x = (bits & 1u) ? __expf(c[0] * 0.125f) * inv : 0.f;
                e.y = (bits & 2u) ? __expf(c[1] * 0.125f) * inv : 0.f;
                e.z = (bits & 4u) ? __expf(c[2] * 0.125f) * inv : 0.f;
                e.w = (bits & 8u) ? __expf(c[3] * 0.125f) * inv : 0.f;
                ev[nt] = e;
                ushort4 pe;
                pe.x = f2bf(e.x); pe.y = f2bf(e.y); pe.z = f2bf(e.z); pe.w = f2bf(e.w);
                const int wbyte = (l15 * 128 + nt * 32 + lg * 8) ^ swzP;  // XOR last
                *(ushort4*)(pbw + wbyte) = pe;
            }
            // PV: own P rows x all d (per-wave in-order DS)
            const bf16x8 ap0 = *(const bf16x8*)(pbw + ab0);
            const bf16x8 ap1 = *(const bf16x8*)(pbw + ab1);
            const unsigned short* vcur = sV2[cur] + sub * 4096;
            #pragma unroll
            for (int nt = 0; nt < 4; ++nt) {
                const int row = nt * 16 + l15, sw = row & 7;   // d-row
                const bf16x8 bv0 = *(const bf16x8*)(vcur + row * 64 + ((lg ^ sw) * 8));
                const bf16x8 bv1 = *(const bf16x8*)(vcur + row * 64 + (((lg + 4) ^ sw) * 8));
                o[nt] = __builtin_amdgcn_mfma_f32_16x16x32_bf16(ap0, bv0, o[nt], 0, 0, 0);
                o[nt] = __builtin_amdgcn_mfma_f32_16x16x32_bf16(ap1, bv1, o[nt], 0, 0, 0);
            }
            // attn stores LAST (newest vmem): never drained by counted waits
            {
                float* astore = arow + kc * 64;
                #pragma unroll
                for (int nt = 0; nt < 4; ++nt)
                    *(float4*)(astore + nt * 16) = ev[nt];
            }
        }
        if (iv < 15) {
            unsigned short* kn = sK2[cur ^ 1];
            unsigned short* vn = sV2[cur ^ 1];
            *(us8*)(kn + ds0)        = nk[0];
            *(us8*)(kn + ds1)        = nk[1];
            *(us8*)(kn + 4096 + ds0) = nk[2];
            *(us8*)(kn + 4096 + ds1) = nk[3];
            *(us8*)(vn + ds0)        = nv[0];
            *(us8*)(vn + ds1)        = nv[1];
            *(us8*)(vn + 4096 + ds0) = nv[2];
            *(us8*)(vn + 4096 + ds1) = nv[3];
        }
        BARRIER_LGKM();
    }

    // epilogue: wave w owns rows w*16..w*16+15 completely
    #pragma unroll
    for (int nt = 0; nt < 4; ++nt)
        #pragma unroll
        for (int r = 0; r < 4; ++r)
            outb[(size_t)(rbase + w * 16 + lg * 4 + r) * D_ + nt * 16 + l15] = o[nt][r];
}

// ================= fp32 deep fallback (needs only 32 KB ws) =================
__global__ __launch_bounds__(256)
void normalize_mask(const void* __restrict__ mask_raw, uint8_t* __restrict__ mask_out)
{
    __shared__ int is_u8;
    const int t = threadIdx.x;
    if (t == 0) is_u8 = 0;
    __syncthreads();
    const int* mi = (const int*)mask_raw;
    int bad = 0;
    for (int i = t; i < 8192; i += 256)
        if ((unsigned)mi[i] > 1u) bad = 1;
    if (bad) atomicOr(&is_u8, 1);
    __syncthreads();
    const int total = BH_ * N_;
    if (is_u8) {
        const uint8_t* m8 = (const uint8_t*)mask_raw;
        for (int i = t; i < total; i += 256) mask_out[i] = m8[i] ? 1 : 0;
    } else {
        for (int i = t; i < total; i += 256) mask_out[i] = (uint8_t)mi[i];
    }
}

__global__ __launch_bounds__(256)
void attn_fused(const float* __restrict__ q, const float* __restrict__ k,
                const float* __restrict__ v, const uint8_t* __restrict__ mask,
                const int* __restrict__ edge, float* __restrict__ out,
                float* __restrict__ attn)
{
    __shared__ float qsT[D_][64 + 4];
    __shared__ float kt [D_][64 + 4];
    __shared__ float vs [64][D_ + 4];
    const int tile = blockIdx.x, bh = blockIdx.y, t = threadIdx.x;
    const int rg = t >> 4, cg = t & 15, r0 = rg * 4, c0 = cg * 4;
    const int row_base = tile * 64;
    const float* qb = q + (size_t)bh * N_ * D_;
    const float* kb = k + (size_t)bh * N_ * D_;
    const float* vb = v + (size_t)bh * N_ * D_;
    const uint8_t* mbp = mask + (size_t)bh * N_;
    const int* ebp = edge + (size_t)(bh & 1) * N_ * N_;
    float* outb = out + (size_t)bh * N_ * D_;
    float* attnb = attn + (size_t)bh * N_ * N_;
    {
        const int rr = t >> 2, dblk = (t & 3) * 16;
        const float* src = qb + (size_t)(row_base + rr) * D_ + dblk;
        #pragma unroll
        for (int qq = 0; qq < 4; ++qq) {
            float4 val = *(const float4*)(src + qq * 4);
            qsT[dblk + qq*4 + 0][rr] = val.x; qsT[dblk + qq*4 + 1][rr] = val.y;
            qsT[dblk + qq*4 + 2][rr] = val.z; qsT[dblk + qq*4 + 3][rr] = val.w;
        }
    }
    float m_i[4], l_i[4];
    #pragma unroll
    for (int i = 0; i < 4; ++i) { m_i[i] = -INFINITY; l_i[i] = 0.f; }
    for (int kc = 0; kc < 32; ++kc) {
        __syncthreads();
        {
            const int ccr = t >> 2, dblk = (t & 3) * 16;
            const float* src = kb + (size_t)(kc * 64 + ccr) * D_ + dblk;
            #pragma unroll
            for (int qq = 0; qq < 4; ++qq) {
                float4 val = *(const float4*)(src + qq * 4);
                kt[dblk + qq*4 + 0][ccr] = val.x; kt[dblk + qq*4 + 1][ccr] = val.y;
                kt[dblk + qq*4 + 2][ccr] = val.z; kt[dblk + qq*4 + 3][ccr] = val.w;
            }
        }
        __syncthreads();
        float sc[4][4];
        #pragma unroll
        for (int i = 0; i < 4; ++i) { sc[i][0]=sc[i][1]=sc[i][2]=sc[i][3]=0.f; }
        for (int d = 0; d < D_; ++d) {
            const float4 qv = *(const float4*)&qsT[d][r0];
            const float4 kv = *(const float4*)&kt[d][c0];
            #pragma unroll
            for (int i = 0; i < 4; ++i) {
                const float qi = (i==0)?qv.x:(i==1)?qv.y:(i==2)?qv.z:qv.w;
                sc[i][0] = fmaf(qi, kv.x, sc[i][0]); sc[i][1] = fmaf(qi, kv.y, sc[i][1]);
                sc[i][2] = fmaf(qi, kv.z, sc[i][2]); sc[i][3] = fmaf(qi, kv.w, sc[i][3]);
            }
        }
        const int cbase = kc * 64 + c0;
        const uint8_t m0 = mbp[cbase], m1 = mbp[cbase+1], m2 = mbp[cbase+2], m3 = mbp[cbase+3];
        #pragma unroll
        for (int i = 0; i < 4; ++i) {
            const int rglob = row_base + r0 + i;
            const int4 e4 = *(const int4*)(ebp + (size_t)rglob * N_ + cbase);
            float s0 = sc[i][0]*0.125f, s1 = sc[i][1]*0.125f, s2 = sc[i][2]*0.125f, s3 = sc[i][3]*0.125f;
            if (e4.x == 0 || m0) s0 = NEGV; if (e4.y == 0 || m1) s1 = NEGV;
            if (e4.z == 0 || m2) s2 = NEGV; if (e4.w == 0 || m3) s3 = NEGV;
            float cmax = fmaxf(fmaxf(s0,s1), fmaxf(s2,s3));
            cmax = fmaxf(cmax, __shfl_xor(cmax,1)); cmax = fmaxf(cmax, __shfl_xor(cmax,2));
            cmax = fmaxf(cmax, __shfl_xor(cmax,4)); cmax = fmaxf(cmax, __shfl_xor(cmax,8));
            const float nm = fmaxf(m_i[i], cmax);
            float ss = __expf(s0-nm)+__expf(s1-nm)+__expf(s2-nm)+__expf(s3-nm);
            ss += __shfl_xor(ss,1); ss += __shfl_xor(ss,2); ss += __shfl_xor(ss,4); ss += __shfl_xor(ss,8);
            l_i[i] = l_i[i]*__expf(m_i[i]-nm) + ss; m_i[i] = nm;
        }
    }
    float inv_l[4];
    #pragma unroll
    for (int i = 0; i < 4; ++i) inv_l[i] = 1.0f / l_i[i];
    float oacc[4][4];
    #pragma unroll
    for (int i = 0; i < 4; ++i) { oacc[i][0]=oacc[i][1]=oacc[i][2]=oacc[i][3]=0.f; }
    for (int kc = 0; kc < 32; ++kc) {
        __syncthreads();
        {
            const int ccr = t >> 2, dblk = (t & 3) * 16;
            const float* src = kb + (size_t)(kc * 64 + ccr) * D_ + dblk;
            #pragma unroll
            for (int qq = 0; qq < 4; ++qq) {
                float4 val = *(const float4*)(src + qq * 4);
                kt[dblk + qq*4 + 0][ccr] = val.x; kt[dblk + qq*4 + 1][ccr] = val.y;
                kt[dblk + qq*4 + 2][ccr] = val.z; kt[dblk + qq*4 + 3][ccr] = val.w;
            }
            const float* srcv = vb + (size_t)(kc * 64 + ccr) * D_ + dblk;
            #pragma unroll
            for (int qq = 0; qq < 4; ++qq)
                *(float4*)&vs[ccr][dblk + qq * 4] = *(const float4*)(srcv + qq * 4);
        }
        __syncthreads();
        float sc[4][4];
        #pragma unroll
        for (int i = 0; i < 4; ++i) { sc[i][0]=sc[i][1]=sc[i][2]=sc[i][3]=0.f; }
        for (int d = 0; d < D_; ++d) {
            const float4 qv = *(const float4*)&qsT[d][r0];
            const float4 kv = *(const float4*)&kt[d][c0];
            #pragma unroll
            for (int i = 0; i < 4; ++i) {
                const float qi = (i==0)?qv.x:(i==1)?qv.y:(i==2)?qv.z:qv.w;
                sc[i][0] = fmaf(qi, kv.x, sc[i][0]); sc[i][1] = fmaf(qi, kv.y, sc[i][1]);
                sc[i][2] = fmaf(qi, kv.z, sc[i][2]); sc[i][3] = fmaf(qi, kv.w, sc[i][3]);
            }
        }
        const int cbase = kc * 64 + c0;
        const uint8_t m0 = mbp[cbase], m1 = mbp[cbase+1], m2 = mbp[cbase+2], m3 = mbp[cbase+3];
        float p[4][4];
        #pragma unroll
        for (int i = 0; i < 4; ++i) {
            const int rglob = row_base + r0 + i;
            const int4 e4 = *(const int4*)(ebp + (size_t)rglob * N_ + cbase);
            float s0 = sc[i][0]*0.125f, s1 = sc[i][1]*0.125f, s2 = sc[i][2]*0.125f, s3 = sc[i][3]*0.125f;
            if (e4.x == 0 || m0) s0 = NEGV; if (e4.y == 0 || m1) s1 = NEGV;
            if (e4.z == 0 || m2) s2 = NEGV; if (e4.w == 0 || m3) s3 = NEGV;
            p[i][0] = __expf(s0-m_i[i])*inv_l[i]; p[i][1] = __expf(s1-m_i[i])*inv_l[i];
            p[i][2] = __expf(s2-m_i[i])*inv_l[i]; p[i][3] = __expf(s3-m_i[i])*inv_l[i];
            *(float4*)&attnb[(size_t)rglob * N_ + cbase] = make_float4(p[i][0],p[i][1],p[i][2],p[i][3]);
        }
        __syncthreads();
        #pragma unroll
        for (int i = 0; i < 4; ++i)
            *(float4*)&kt[r0 + i][c0] = make_float4(p[i][0],p[i][1],p[i][2],p[i][3]);
        __syncthreads();
        for (int c4 = 0; c4 < 64; c4 += 4) {
            float prr[4][4];
            #pragma unroll
            for (int i = 0; i < 4; ++i) {
                const float4 tmp = *(const float4*)&kt[r0 + i][c4];
                prr[i][0]=tmp.x; prr[i][1]=tmp.y; prr[i][2]=tmp.z; prr[i][3]=tmp.w;
            }
            #pragma unroll
            for (int cc = 0; cc < 4; ++cc) {
                const float4 vv = *(const float4*)&vs[c4 + cc][c0];
                #pragma unroll
                for (int i = 0; i < 4; ++i) {
                    oacc[i][0] = fmaf(prr[i][cc], vv.x, oacc[i][0]);
                    oacc[i][1] = fmaf(prr[i][cc], vv.y, oacc[i][1]);
                    oacc[i][2] = fmaf(prr[i][cc], vv.z, oacc[i][2]);
                    oacc[i][3] = fmaf(prr[i][cc], vv.w, oacc[i][3]);
                }
            }
        }
    }
    #pragma unroll
    for (int i = 0; i < 4; ++i)
        *(float4*)&outb[(size_t)(row_base + r0 + i) * D_ + c0] =
            make_float4(oacc[i][0], oacc[i][1], oacc[i][2], oacc[i][3]);
}

extern "C" void kernel_launch(void* const* d_in, const int* in_sizes, int n_in,
                              void* d_out, int out_size, void* d_ws, size_t ws_size,
                              hipStream_t stream) {
    const float* q    = (const float*)d_in[0];
    const float* k    = (const float*)d_in[1];
    const float* v    = (const float*)d_in[2];
    // d_in[3] = k2 (unused by the reference)
    const void*  mraw = d_in[4];
    const int*   edge = (const int*)d_in[5];

    float* out  = (float*)d_out;                         // [16][2048][64]
    float* attn = (float*)d_out + (size_t)BH_ * N_ * D_; // [16][2048][2048]

    char* ws = (char*)d_ws;

    if (ws_size < (size_t)WS_V6) {
        uint8_t* mask_u8 = (uint8_t*)(ws + OFF_MASKU8);
        normalize_mask<<<1, 256, 0, stream>>>(mraw, mask_u8);
        attn_fused<<<dim3(32, 16), 256, 0, stream>>>(q, k, v, mask_u8, edge, out, attn);
        return;
    }

    unsigned long long* mbits = (unsigned long long*)(ws + OFF_MBITS);
    unsigned short*     e16   = (unsigned short*)(ws + OFF_EBITS);
    unsigned short*     qbf   = (unsigned short*)(ws + OFF_QBF);
    unsigned short*     kbf   = (unsigned short*)(ws + OFF_KBF);
    unsigned short*     vT    = (unsigned short*)(ws + OFF_VT);

    prep_all<<<dim3(2576), 256, 0, stream>>>(q, k, v, mraw, edge,
                                             qbf, kbf, vT, e16, mbits);
    // bh fastest-varying -> XCD = bh % 8 -> 2 heads per XCD L2 (T1)
    attn_v12<<<dim3(BH_, N_ / 64), 256, 0, stream>>>(
        qbf, kbf, vT, (const unsigned long long*)e16, mbits, out, attn);
}